// Round 9
// baseline (417.370 us; speedup 1.0000x reference)
//
#include <hip/hip_runtime.h>

#define BSZ  5
#define PROJ 1000
#define DET  513
#define IMG  362
#define NPIX (IMG * IMG)          // 131044
#define SINO (PROJ * DET)         // 513000
#define NNZ  20000000

#define NSHARD     4
#define SHARD_COLS (SINO / NSHARD)   // 128250
#define RB_SHIFT   10
#define RB_PX      1024
#define NRBIN      128
#define NBIN       (NRBIN * NSHARD)  // 512

#define SCAT_BLOCKS  256
#define SCAT_THREADS 1024
#define CHUNK        78128           // ceil(NNZ/256) rounded to mult of 16
#define TILE         4096

#define ACC_THREADS  512

#define FXSCALE 262144.0f            // 2^18
#define FXINV   (1.0f / 262144.0f)
#define FXBIAS  4194304              // 2^22

typedef int      i32x4 __attribute__((ext_vector_type(4)));
typedef float    f32x4 __attribute__((ext_vector_type(4)));
typedef float    f32x2 __attribute__((ext_vector_type(2)));
typedef unsigned u32x4 __attribute__((ext_vector_type(4)));

// no-return LDS atomics (fire-and-forget).
__device__ __forceinline__ unsigned lds_off(const void* p) {
    return (unsigned)(size_t)p;
}
__device__ __forceinline__ void ds_add_u32_nr(unsigned off, unsigned v) {
    asm volatile("ds_add_u32 %0, %1" :: "v"(off), "v"(v) : "memory");
}
__device__ __forceinline__ void ds_add_u64_nr(unsigned off, unsigned long long v) {
    asm volatile("ds_add_u64 %0, %1" :: "v"(off), "v"(v) : "memory");
}
// per-wave drain of outstanding DS ops: guarantees our inline-asm adds have
// COMPLETED (hence are globally visible in LDS) before the wave reaches the
// following __syncthreads, independent of compiler waitcnt modeling.
__device__ __forceinline__ void lgkm_drain() {
    asm volatile("s_waitcnt lgkmcnt(0)" ::: "memory");
}

__device__ __forceinline__ int bin_of(int row, int col) {
    return ((row >> RB_SHIFT) << 2) | (col / SHARD_COLS);
}

// ---------------- fast path kernels ----------------

// sino -> bf16 packed table: [col] = u32x4 {b0|b1<<16, b2|b3<<16, b4, 0}
__global__ void k_sino_bf16(const float* __restrict__ sino, u32x4* __restrict__ sino_b) {
    const int c = blockIdx.x * blockDim.x + threadIdx.x;
    if (c < SINO) {
        unsigned b[5];
#pragma unroll
        for (int k = 0; k < 5; ++k) {
            const unsigned u = __float_as_uint(sino[(size_t)k * SINO + c]);
            b[k] = (u + 0x7FFFu + ((u >> 16) & 1u)) >> 16;   // RNE to bf16
        }
        u32x4 o;
        o.x = b[0] | (b[1] << 16);
        o.y = b[2] | (b[3] << 16);
        o.z = b[4];
        o.w = 0u;
        sino_b[c] = o;
    }
}

// pass A: per-(block,bin) exact counts
__global__ __launch_bounds__(SCAT_THREADS) void k_count(
        const int* __restrict__ rows, const int* __restrict__ cols,
        unsigned* __restrict__ cnt) {
    __shared__ unsigned c[NBIN];
    const int t = threadIdx.x;
    if (t < NBIN) c[t] = 0u;
    __syncthreads();
    const int lo = blockIdx.x * CHUNK;
    const int hi = (lo + CHUNK < NNZ) ? lo + CHUNK : NNZ;
    if (lo < hi) {
        for (int i4 = lo / 4 + t; i4 * 4 < hi; i4 += SCAT_THREADS) {
            const i32x4 r = __builtin_nontemporal_load(((const i32x4*)rows) + i4);
            const i32x4 q = __builtin_nontemporal_load(((const i32x4*)cols) + i4);
            ds_add_u32_nr(lds_off(&c[bin_of(r.x, q.x)]), 1u);
            ds_add_u32_nr(lds_off(&c[bin_of(r.y, q.y)]), 1u);
            ds_add_u32_nr(lds_off(&c[bin_of(r.z, q.z)]), 1u);
            ds_add_u32_nr(lds_off(&c[bin_of(r.w, q.w)]), 1u);
        }
    }
    lgkm_drain();
    __syncthreads();
    if (t < NBIN) cnt[(size_t)blockIdx.x * NBIN + t] = c[t];
}

// per-bin totals: block b reduces cnt[*][b]
__global__ __launch_bounds__(SCAT_BLOCKS) void k_tot(
        const unsigned* __restrict__ cnt, unsigned* __restrict__ tot) {
    __shared__ unsigned s[SCAT_BLOCKS];
    const int b = blockIdx.x, t = threadIdx.x;
    s[t] = cnt[(size_t)t * NBIN + b];
    __syncthreads();
    for (int o = SCAT_BLOCKS / 2; o > 0; o >>= 1) {
        if (t < o) s[t] += s[t + o];
        __syncthreads();
    }
    if (t == 0) tot[b] = s[0];
}

// exclusive scan of tot -> binoff
__global__ __launch_bounds__(NBIN) void k_scan(
        const unsigned* __restrict__ tot, unsigned* __restrict__ binoff) {
    __shared__ unsigned s[NBIN];
    const int t = threadIdx.x;
    const unsigned my = tot[t];
    s[t] = my;
    __syncthreads();
    for (int o = 1; o < NBIN; o <<= 1) {
        const unsigned v = (t >= o) ? s[t - o] : 0u;
        __syncthreads();
        s[t] += v;
        __syncthreads();
    }
    binoff[t] = s[t] - my;
    if (t == NBIN - 1) binoff[NBIN] = (unsigned)NNZ;
}

// per-(block,bin) global base positions
__global__ __launch_bounds__(SCAT_BLOCKS) void k_base(
        const unsigned* __restrict__ cnt, const unsigned* __restrict__ binoff,
        unsigned* __restrict__ base) {
    __shared__ unsigned s[SCAT_BLOCKS];
    const int b = blockIdx.x, t = threadIdx.x;
    const unsigned my = cnt[(size_t)t * NBIN + b];
    s[t] = my;
    __syncthreads();
    for (int o = 1; o < SCAT_BLOCKS; o <<= 1) {
        const unsigned v = (t >= o) ? s[t - o] : 0u;
        __syncthreads();
        s[t] += v;
        __syncthreads();
    }
    base[(size_t)t * NBIN + b] = binoff[b] + s[t] - my;
}

// pass B: tile-local counting sort in LDS, then coalesced per-bin-run emission
__global__ __launch_bounds__(SCAT_THREADS) void k_scatter(
        const float* __restrict__ vals, const int* __restrict__ rows,
        const int* __restrict__ cols, const unsigned* __restrict__ base,
        unsigned long long* __restrict__ rec) {
    __shared__ unsigned cnt[NBIN];
    __shared__ unsigned toff[NBIN];
    __shared__ unsigned cur[NBIN];
    __shared__ unsigned bs2[NBIN];
    __shared__ unsigned long long sdata[TILE];   // 32 KB
    __shared__ unsigned short sbin[TILE];        //  8 KB
    const int t = threadIdx.x;
    const int lo = blockIdx.x * CHUNK;
    const int hi = (lo + CHUNK < NNZ) ? lo + CHUNK : NNZ;
    if (lo >= hi) return;

    if (t < NBIN) bs2[t] = base[(size_t)blockIdx.x * NBIN + t];

    for (int tb = lo; tb < hi; tb += TILE) {
        const int n = (tb + TILE < hi) ? TILE : (hi - tb);   // always mult of 4
        if (t < NBIN) cnt[t] = 0u;
        __syncthreads();

        // load 4 records into registers; count bins (no-rtn + explicit drain)
        i32x4 r, q; f32x4 v;
        int bn0 = 0, bn1 = 0, bn2 = 0, bn3 = 0;
        const bool act = (t * 4) < n;
        if (act) {
            const int g4 = (tb + t * 4) >> 2;
            r = __builtin_nontemporal_load(((const i32x4*)rows) + g4);
            q = __builtin_nontemporal_load(((const i32x4*)cols) + g4);
            v = __builtin_nontemporal_load(((const f32x4*)vals) + g4);
            bn0 = bin_of(r.x, q.x);
            bn1 = bin_of(r.y, q.y);
            bn2 = bin_of(r.z, q.z);
            bn3 = bin_of(r.w, q.w);
            ds_add_u32_nr(lds_off(&cnt[bn0]), 1u);
            ds_add_u32_nr(lds_off(&cnt[bn1]), 1u);
            ds_add_u32_nr(lds_off(&cnt[bn2]), 1u);
            ds_add_u32_nr(lds_off(&cnt[bn3]), 1u);
        }
        lgkm_drain();
        __syncthreads();

        // exclusive scan of cnt -> toff/cur (barriered Hillis-Steele, proven pattern)
        unsigned my = 0u;
        if (t < NBIN) { my = cnt[t]; toff[t] = my; }
        __syncthreads();
        for (int o = 1; o < NBIN; o <<= 1) {
            unsigned x = 0u;
            if (t < NBIN && t >= o) x = toff[t - o];
            __syncthreads();
            if (t < NBIN) toff[t] += x;
            __syncthreads();
        }
        if (t < NBIN) { const unsigned e = toff[t] - my; toff[t] = e; cur[t] = e; }
        __syncthreads();

        // rank-claim (tracked rtn atomics) + write sorted records into LDS
        if (act) {
#define RANK(BN, RR, QQ, VV) do {                                          \
            const unsigned slot = atomicAdd(&cur[BN], 1u);                 \
            const unsigned packed =                                        \
                ((unsigned)((RR) & (RB_PX - 1)) << 19) | (unsigned)(QQ);   \
            sdata[slot] = ((unsigned long long)packed << 32)               \
                        | (unsigned long long)__float_as_uint(VV);         \
            sbin[slot] = (unsigned short)(BN);                             \
        } while (0)
            RANK(bn0, r.x, q.x, v.x);
            RANK(bn1, r.y, q.y, v.y);
            RANK(bn2, r.z, q.z, v.z);
            RANK(bn3, r.w, q.w, v.w);
#undef RANK
        }
        __syncthreads();

        // emission: consecutive threads -> consecutive addresses per bin-run
        for (int j = t; j < n; j += SCAT_THREADS) {
            const unsigned long long d = sdata[j];
            const int sb = (int)sbin[j];
            const unsigned pos = bs2[sb] + ((unsigned)j - toff[sb]);
            __builtin_nontemporal_store(d, rec + pos);
        }
        __syncthreads();

        if (t < NBIN) bs2[t] += cnt[t];
        __syncthreads();
    }
}

// accumulate one bin in LDS with fixed-point packed u64 no-rtn atomics
__global__ __launch_bounds__(ACC_THREADS) void k_accum(
        const f32x2* __restrict__ rec, const u32x4* __restrict__ sino_b,
        const unsigned* __restrict__ binoff, float* __restrict__ acc) {
    __shared__ unsigned long long l8[RB_PX * 5];   // 40 KB
    const int t = threadIdx.x;
    for (int j = t; j < RB_PX * 5; j += ACC_THREADS) l8[j] = 0ull;
    __syncthreads();
    const int bin = blockIdx.x;
    const unsigned lo = binoff[bin], hi = binoff[bin + 1];
    for (unsigned i = lo + t; i < hi; i += ACC_THREADS) {
        const f32x2 rc = __builtin_nontemporal_load(rec + i);
        const unsigned u = __float_as_uint(rc.y);
        const int col = (int)(u & 0x7FFFFu);
        const int lr  = (int)(u >> 19);
        const u32x4 sv = sino_b[col];
        const float v = rc.x;
        const int q0 = __float2int_rn(v * __uint_as_float(sv.x << 16)         * FXSCALE);
        const int q1 = __float2int_rn(v * __uint_as_float(sv.x & 0xFFFF0000u) * FXSCALE);
        const int q2 = __float2int_rn(v * __uint_as_float(sv.y << 16)         * FXSCALE);
        const int q3 = __float2int_rn(v * __uint_as_float(sv.y & 0xFFFF0000u) * FXSCALE);
        const int q4 = __float2int_rn(v * __uint_as_float(sv.z << 16)         * FXSCALE);
        const int q5 = __float2int_rn(v * FXSCALE);
        const unsigned b = lds_off(&l8[(unsigned)lr * 5u]);
        ds_add_u64_nr(b,
            ((unsigned long long)(unsigned)q1 << 32) | (unsigned)(q0 + FXBIAS));
        ds_add_u64_nr(b + 8,
            ((unsigned long long)(unsigned)q3 << 32) | (unsigned)(q2 + FXBIAS));
        ds_add_u64_nr(b + 16,
            ((unsigned long long)(unsigned)q5 << 32) | (unsigned)(q4 + FXBIAS));
        ds_add_u32_nr(b + 24, 1u);
    }
    lgkm_drain();
    __syncthreads();
    float* dst = acc + (size_t)bin * (RB_PX * 6);
    for (int px = t; px < RB_PX; px += ACC_THREADS) {
        const unsigned long long a0 = l8[px * 5 + 0];
        const unsigned long long a1 = l8[px * 5 + 1];
        const unsigned long long a2 = l8[px * 5 + 2];
        const unsigned n = (unsigned)(l8[px * 5 + 3] & 0xFFFFFFFFull);
        const long long nb = (long long)n * FXBIAS;
        float* d = dst + px * 6;
        d[0] = (float)((long long)(unsigned)(a0 & 0xFFFFFFFFull) - nb) * FXINV;
        d[1] = (float)((int)(a0 >> 32)) * FXINV;
        d[2] = (float)((long long)(unsigned)(a1 & 0xFFFFFFFFull) - nb) * FXINV;
        d[3] = (float)((int)(a1 >> 32)) * FXINV;
        d[4] = (float)((long long)(unsigned)(a2 & 0xFFFFFFFFull) - nb) * FXINV;
        d[5] = (float)((int)(a2 >> 32)) * FXINV;
    }
}

// sum 4 shards per pixel, divide, write [BSZ][NPIX]
__global__ void k_reduce(const float* __restrict__ acc, float* __restrict__ out) {
    const int p = blockIdx.x * blockDim.x + threadIdx.x;
    if (p < NPIX) {
        const int rbin = p >> RB_SHIFT, lr = p & (RB_PX - 1);
        float n0 = 0.f, n1 = 0.f, n2 = 0.f, n3 = 0.f, n4 = 0.f, den = 0.f;
#pragma unroll
        for (int s = 0; s < NSHARD; ++s) {
            const float* b = acc + ((size_t)(rbin * NSHARD + s) * RB_PX + lr) * 6;
            n0 += b[0]; n1 += b[1]; n2 += b[2];
            n3 += b[3]; n4 += b[4]; den += b[5];
        }
        const float inv = 1.f / den;
        out[0 * (size_t)NPIX + p] = n0 * inv;
        out[1 * (size_t)NPIX + p] = n1 * inv;
        out[2 * (size_t)NPIX + p] = n2 * inv;
        out[3 * (size_t)NPIX + p] = n3 * inv;
        out[4 * (size_t)NPIX + p] = n4 * inv;
    }
}

// ---------------- fallback kernels (small workspace) ----------------

__global__ void bp_scatter_fb_kernel(const float* __restrict__ sino,
                                     const float* __restrict__ vals,
                                     const int*   __restrict__ rows,
                                     const int*   __restrict__ cols,
                                     float* __restrict__ acc) {
    const long long stride = (long long)gridDim.x * blockDim.x;
    for (long long i = (long long)blockIdx.x * blockDim.x + threadIdx.x;
         i < NNZ; i += stride) {
        const float v = vals[i];
        const int   r = rows[i];
        const int   c = cols[i];
        atomicAdd(acc + (size_t)BSZ * NPIX + r, v);
#pragma unroll
        for (int b = 0; b < BSZ; ++b)
            atomicAdd(acc + (size_t)b * NPIX + r, v * sino[(size_t)b * SINO + c]);
    }
}

__global__ void bp_divide_fb_kernel(const float* __restrict__ acc,
                                    float* __restrict__ out) {
    const int i = blockIdx.x * blockDim.x + threadIdx.x;
    if (i < BSZ * NPIX) {
        const int p = i % NPIX;
        out[i] = acc[i] / acc[(size_t)BSZ * NPIX + p];
    }
}

// ---------------- launch ----------------

extern "C" void kernel_launch(void* const* d_in, const int* in_sizes, int n_in,
                              void* d_out, int out_size, void* d_ws, size_t ws_size,
                              hipStream_t stream) {
    const float* sino = (const float*)d_in[0];
    const float* vals = (const float*)d_in[1];
    const int*   rows = (const int*)d_in[2];
    const int*   cols = (const int*)d_in[3];
    float* out = (float*)d_out;

    // workspace layout (bytes, all 16B-aligned) — identical to round 7:
    //   rec    : NNZ * 8                  = 160,000,000
    //   sino_b : SINO * 16                =   8,208,000
    //   acc    : NBIN * RB_PX * 6 * 4     =  12,582,912
    //   cnt    : SCAT_BLOCKS * NBIN * 4   =     524,288
    //   base   : SCAT_BLOCKS * NBIN * 4   =     524,288
    //   tot    : NBIN * 4
    //   binoff : (NBIN+1) * 4
    const size_t rec_b    = (size_t)NNZ * 8;
    const size_t sino_b_b = (size_t)SINO * 16;
    const size_t acc_b    = (size_t)NBIN * RB_PX * 6 * 4;
    const size_t cnt_b    = (size_t)SCAT_BLOCKS * NBIN * 4;
    const size_t need = rec_b + sino_b_b + acc_b + 2 * cnt_b + (size_t)(NBIN + NBIN + 1 + 8) * 4;

    if (ws_size >= need) {
        char* w = (char*)d_ws;
        unsigned long long* rec = (unsigned long long*)w;   w += rec_b;
        u32x4*    sinob  = (u32x4*)w;                       w += sino_b_b;
        float*    acc    = (float*)w;                       w += acc_b;
        unsigned* cnt    = (unsigned*)w;                    w += cnt_b;
        unsigned* base   = (unsigned*)w;                    w += cnt_b;
        unsigned* tot    = (unsigned*)w;                    w += (size_t)NBIN * 4;
        unsigned* binoff = (unsigned*)w;

        k_sino_bf16<<<(SINO + 255) / 256, 256, 0, stream>>>(sino, sinob);
        k_count<<<SCAT_BLOCKS, SCAT_THREADS, 0, stream>>>(rows, cols, cnt);
        k_tot<<<NBIN, SCAT_BLOCKS, 0, stream>>>(cnt, tot);
        k_scan<<<1, NBIN, 0, stream>>>(tot, binoff);
        k_base<<<NBIN, SCAT_BLOCKS, 0, stream>>>(cnt, binoff, base);
        k_scatter<<<SCAT_BLOCKS, SCAT_THREADS, 0, stream>>>(vals, rows, cols, base, rec);
        k_accum<<<NBIN, ACC_THREADS, 0, stream>>>((const f32x2*)rec, sinob, binoff, acc);
        k_reduce<<<(NPIX + 255) / 256, 256, 0, stream>>>(acc, out);
    } else {
        float* acc = (float*)d_ws;
        (void)hipMemsetAsync(acc, 0, (size_t)(BSZ + 1) * NPIX * sizeof(float), stream);
        bp_scatter_fb_kernel<<<2048, 256, 0, stream>>>(sino, vals, rows, cols, acc);
        bp_divide_fb_kernel<<<(BSZ * NPIX + 255) / 256, 256, 0, stream>>>(acc, out);
    }
}

// Round 11
// 415.139 us; speedup vs baseline: 1.0054x; 1.0054x over previous
//
#include <hip/hip_runtime.h>

#define BSZ  5
#define PROJ 1000
#define DET  513
#define IMG  362
#define NPIX (IMG * IMG)          // 131044
#define SINO (PROJ * DET)         // 513000
#define NNZ  20000000

#define NSHARD     4
#define SHARD_COLS (SINO / NSHARD)   // 128250
#define RB_SHIFT   10
#define RB_PX      1024
#define NRBIN      128
#define NBIN       (NRBIN * NSHARD)  // 512

#define SCAT_BLOCKS  256
#define SCAT_THREADS 1024
#define CHUNK        78128           // ceil(NNZ/256) rounded to mult of 16
#define TILE         4096

#define ACC_THREADS  512

#define FXSCALE 262144.0f            // 2^18
#define FXINV   (1.0f / 262144.0f)
#define FXBIAS  4194304              // 2^22

typedef int      i32x4 __attribute__((ext_vector_type(4)));
typedef float    f32x4 __attribute__((ext_vector_type(4)));
typedef float    f32x2 __attribute__((ext_vector_type(2)));
typedef unsigned u32x4 __attribute__((ext_vector_type(4)));

// no-return LDS atomics (fire-and-forget).
__device__ __forceinline__ unsigned lds_off(const void* p) {
    return (unsigned)(size_t)p;
}
__device__ __forceinline__ void ds_add_u32_nr(unsigned off, unsigned v) {
    asm volatile("ds_add_u32 %0, %1" :: "v"(off), "v"(v) : "memory");
}
__device__ __forceinline__ void ds_add_u64_nr(unsigned off, unsigned long long v) {
    asm volatile("ds_add_u64 %0, %1" :: "v"(off), "v"(v) : "memory");
}
// per-wave drain: inline-asm DS ops COMPLETE before the following barrier.
__device__ __forceinline__ void lgkm_drain() {
    asm volatile("s_waitcnt lgkmcnt(0)" ::: "memory");
}

__device__ __forceinline__ int bin_of(int row, int col) {
    return ((row >> RB_SHIFT) << 2) | (col / SHARD_COLS);
}

// ---------------- fast path kernels ----------------

// sino -> bf16 packed table: [col] = u32x4 {b0|b1<<16, b2|b3<<16, b4, 0}
__global__ void k_sino_bf16(const float* __restrict__ sino, u32x4* __restrict__ sino_b) {
    const int c = blockIdx.x * blockDim.x + threadIdx.x;
    if (c < SINO) {
        unsigned b[5];
#pragma unroll
        for (int k = 0; k < 5; ++k) {
            const unsigned u = __float_as_uint(sino[(size_t)k * SINO + c]);
            b[k] = (u + 0x7FFFu + ((u >> 16) & 1u)) >> 16;   // RNE to bf16
        }
        u32x4 o;
        o.x = b[0] | (b[1] << 16);
        o.y = b[2] | (b[3] << 16);
        o.z = b[4];
        o.w = 0u;
        sino_b[c] = o;
    }
}

// pass A: per-(block,bin) exact counts
__global__ __launch_bounds__(SCAT_THREADS) void k_count(
        const int* __restrict__ rows, const int* __restrict__ cols,
        unsigned* __restrict__ cnt) {
    __shared__ unsigned c[NBIN];
    const int t = threadIdx.x;
    if (t < NBIN) c[t] = 0u;
    __syncthreads();
    const int lo = blockIdx.x * CHUNK;
    const int hi = (lo + CHUNK < NNZ) ? lo + CHUNK : NNZ;
    if (lo < hi) {
        for (int i4 = lo / 4 + t; i4 * 4 < hi; i4 += SCAT_THREADS) {
            const i32x4 r = __builtin_nontemporal_load(((const i32x4*)rows) + i4);
            const i32x4 q = __builtin_nontemporal_load(((const i32x4*)cols) + i4);
            ds_add_u32_nr(lds_off(&c[bin_of(r.x, q.x)]), 1u);
            ds_add_u32_nr(lds_off(&c[bin_of(r.y, q.y)]), 1u);
            ds_add_u32_nr(lds_off(&c[bin_of(r.z, q.z)]), 1u);
            ds_add_u32_nr(lds_off(&c[bin_of(r.w, q.w)]), 1u);
        }
    }
    lgkm_drain();
    __syncthreads();
    if (t < NBIN) cnt[(size_t)blockIdx.x * NBIN + t] = c[t];
}

// per-bin totals: block b reduces cnt[*][b]
__global__ __launch_bounds__(SCAT_BLOCKS) void k_tot(
        const unsigned* __restrict__ cnt, unsigned* __restrict__ tot) {
    __shared__ unsigned s[SCAT_BLOCKS];
    const int b = blockIdx.x, t = threadIdx.x;
    s[t] = cnt[(size_t)t * NBIN + b];
    __syncthreads();
    for (int o = SCAT_BLOCKS / 2; o > 0; o >>= 1) {
        if (t < o) s[t] += s[t + o];
        __syncthreads();
    }
    if (t == 0) tot[b] = s[0];
}

// exclusive scan of tot -> binoff
__global__ __launch_bounds__(NBIN) void k_scan(
        const unsigned* __restrict__ tot, unsigned* __restrict__ binoff) {
    __shared__ unsigned s[NBIN];
    const int t = threadIdx.x;
    const unsigned my = tot[t];
    s[t] = my;
    __syncthreads();
    for (int o = 1; o < NBIN; o <<= 1) {
        const unsigned v = (t >= o) ? s[t - o] : 0u;
        __syncthreads();
        s[t] += v;
        __syncthreads();
    }
    binoff[t] = s[t] - my;
    if (t == NBIN - 1) binoff[NBIN] = (unsigned)NNZ;
}

// per-(block,bin) global base positions
__global__ __launch_bounds__(SCAT_BLOCKS) void k_base(
        const unsigned* __restrict__ cnt, const unsigned* __restrict__ binoff,
        unsigned* __restrict__ base) {
    __shared__ unsigned s[SCAT_BLOCKS];
    const int b = blockIdx.x, t = threadIdx.x;
    const unsigned my = cnt[(size_t)t * NBIN + b];
    s[t] = my;
    __syncthreads();
    for (int o = 1; o < SCAT_BLOCKS; o <<= 1) {
        const unsigned v = (t >= o) ? s[t - o] : 0u;
        __syncthreads();
        s[t] += v;
        __syncthreads();
    }
    base[(size_t)t * NBIN + b] = binoff[b] + s[t] - my;
}

// pass B: tile-local counting sort (fused count+claim, shfl wave-scan, coalesced emit)
// LDS record: [63:55]=bin(9) [54:26]=packed(29)=lr(10)|col(19) [25:0]=val26
__global__ __launch_bounds__(SCAT_THREADS) void k_scatter(
        const float* __restrict__ vals, const int* __restrict__ rows,
        const int* __restrict__ cols, const unsigned* __restrict__ base,
        unsigned long long* __restrict__ rec) {
    __shared__ unsigned cnt[NBIN];
    __shared__ unsigned toff[NBIN];
    __shared__ unsigned ebase[NBIN];
    __shared__ unsigned bs2[NBIN];
    __shared__ unsigned wsum[8];
    __shared__ unsigned long long sdata[TILE];   // 32 KB
    const int t = threadIdx.x;
    const int lane = t & 63;
    const int lo = blockIdx.x * CHUNK;
    const int hi = (lo + CHUNK < NNZ) ? lo + CHUNK : NNZ;
    if (lo >= hi) return;

    if (t < NBIN) { bs2[t] = base[(size_t)blockIdx.x * NBIN + t]; cnt[t] = 0u; }
    __syncthreads();

    for (int tb = lo; tb < hi; tb += TILE) {
        const int n = (tb + TILE < hi) ? TILE : (hi - tb);   // always mult of 16

        // Phase B: load 4 records, claim slots (tracked rtn atomic = fused count+rank)
        unsigned long long r8[4];
        unsigned sl[4];
        const bool act = (t * 4) < n;    // n mult of 16 => whole 4-group in range
        if (act) {
            const int i4 = (tb + t * 4) >> 2;
            const i32x4 r = __builtin_nontemporal_load(((const i32x4*)rows) + i4);
            const i32x4 q = __builtin_nontemporal_load(((const i32x4*)cols) + i4);
            const f32x4 v = __builtin_nontemporal_load(((const f32x4*)vals) + i4);
#pragma unroll
            for (int k = 0; k < 4; ++k) {
                const int rr = (k == 0) ? r.x : (k == 1) ? r.y : (k == 2) ? r.z : r.w;
                const int qq = (k == 0) ? q.x : (k == 1) ? q.y : (k == 2) ? q.z : q.w;
                const float vf = (k == 0) ? v.x : (k == 1) ? v.y : (k == 2) ? v.z : v.w;
                const unsigned bn = (unsigned)bin_of(rr, qq);
                const unsigned packed =
                    ((unsigned)(rr & (RB_PX - 1)) << 19) | (unsigned)qq;
                const unsigned v26 = __float_as_uint(vf) >> 6;
                r8[k] = ((unsigned long long)bn << 55)
                      | ((unsigned long long)packed << 26)
                      | (unsigned long long)v26;
                sl[k] = atomicAdd(&cnt[bn], 1u);
            }
        }
        __syncthreads();

        // Phase C: exclusive scan of cnt[512] via per-wave __shfl_up (waves 0..7)
        unsigned x = 0u, incl = 0u;
        if (t < NBIN) {
            x = cnt[t];
            incl = x;
#pragma unroll
            for (int o = 1; o < 64; o <<= 1) {
                const unsigned y = __shfl_up(incl, (unsigned)o, 64);
                if (lane >= o) incl += y;
            }
            if (lane == 63) wsum[t >> 6] = incl;
        }
        __syncthreads();
        if (t < NBIN) {
            unsigned wo = 0u;
            const int w = t >> 6;
            for (int k = 0; k < w; ++k) wo += wsum[k];
            const unsigned e = wo + incl - x;        // exclusive prefix for bin t
            toff[t] = e;
            ebase[t] = bs2[t] - e;
        }
        __syncthreads();

        // Phase D: place records sorted into LDS
        if (act) {
#pragma unroll
            for (int k = 0; k < 4; ++k) {
                const unsigned bn = (unsigned)(r8[k] >> 55);
                sdata[toff[bn] + sl[k]] = r8[k];
            }
        }
        __syncthreads();

        // Phase E: emission — consecutive threads -> consecutive addresses per bin-run
        for (int j = t; j < n; j += SCAT_THREADS) {
            const unsigned long long u = sdata[j];
            const unsigned sb = (unsigned)(u >> 55);
            const unsigned packed = ((unsigned)(u >> 26)) & 0x1FFFFFFFu;
            const unsigned vbits = ((unsigned)u & 0x03FFFFFFu) << 6;
            const unsigned pos = ebase[sb] + (unsigned)j;
            __builtin_nontemporal_store(
                ((unsigned long long)packed << 32) | (unsigned long long)vbits,
                rec + pos);
        }
        __syncthreads();

        // Phase F: advance segment cursors, reset counters
        if (t < NBIN) { bs2[t] += cnt[t]; cnt[t] = 0u; }
        __syncthreads();
    }
}

// accumulate one bin in LDS with fixed-point packed u64 no-rtn atomics
__global__ __launch_bounds__(ACC_THREADS) void k_accum(
        const f32x2* __restrict__ rec, const u32x4* __restrict__ sino_b,
        const unsigned* __restrict__ binoff, float* __restrict__ acc) {
    __shared__ unsigned long long l8[RB_PX * 5];   // 40 KB
    const int t = threadIdx.x;
    for (int j = t; j < RB_PX * 5; j += ACC_THREADS) l8[j] = 0ull;
    __syncthreads();
    const int bin = blockIdx.x;
    const unsigned lo = binoff[bin], hi = binoff[bin + 1];
    for (unsigned i = lo + t; i < hi; i += ACC_THREADS) {
        const f32x2 rc = __builtin_nontemporal_load(rec + i);
        const unsigned u = __float_as_uint(rc.y);
        const int col = (int)(u & 0x7FFFFu);
        const int lr  = (int)(u >> 19);
        const u32x4 sv = sino_b[col];
        const float v = rc.x;
        const int q0 = __float2int_rn(v * __uint_as_float(sv.x << 16)         * FXSCALE);
        const int q1 = __float2int_rn(v * __uint_as_float(sv.x & 0xFFFF0000u) * FXSCALE);
        const int q2 = __float2int_rn(v * __uint_as_float(sv.y << 16)         * FXSCALE);
        const int q3 = __float2int_rn(v * __uint_as_float(sv.y & 0xFFFF0000u) * FXSCALE);
        const int q4 = __float2int_rn(v * __uint_as_float(sv.z << 16)         * FXSCALE);
        const int q5 = __float2int_rn(v * FXSCALE);
        const unsigned b = lds_off(&l8[(unsigned)lr * 5u]);
        ds_add_u64_nr(b,
            ((unsigned long long)(unsigned)q1 << 32) | (unsigned)(q0 + FXBIAS));
        ds_add_u64_nr(b + 8,
            ((unsigned long long)(unsigned)q3 << 32) | (unsigned)(q2 + FXBIAS));
        ds_add_u64_nr(b + 16,
            ((unsigned long long)(unsigned)q5 << 32) | (unsigned)(q4 + FXBIAS));
        ds_add_u32_nr(b + 24, 1u);
    }
    lgkm_drain();
    __syncthreads();
    float* dst = acc + (size_t)bin * (RB_PX * 6);
    for (int px = t; px < RB_PX; px += ACC_THREADS) {
        const unsigned long long a0 = l8[px * 5 + 0];
        const unsigned long long a1 = l8[px * 5 + 1];
        const unsigned long long a2 = l8[px * 5 + 2];
        const unsigned n = (unsigned)(l8[px * 5 + 3] & 0xFFFFFFFFull);
        const long long nb = (long long)n * FXBIAS;
        float* d = dst + px * 6;
        d[0] = (float)((long long)(unsigned)(a0 & 0xFFFFFFFFull) - nb) * FXINV;
        d[1] = (float)((int)(a0 >> 32)) * FXINV;
        d[2] = (float)((long long)(unsigned)(a1 & 0xFFFFFFFFull) - nb) * FXINV;
        d[3] = (float)((int)(a1 >> 32)) * FXINV;
        d[4] = (float)((long long)(unsigned)(a2 & 0xFFFFFFFFull) - nb) * FXINV;
        d[5] = (float)((int)(a2 >> 32)) * FXINV;
    }
}

// sum 4 shards per pixel, divide, write [BSZ][NPIX]
__global__ void k_reduce(const float* __restrict__ acc, float* __restrict__ out) {
    const int p = blockIdx.x * blockDim.x + threadIdx.x;
    if (p < NPIX) {
        const int rbin = p >> RB_SHIFT, lr = p & (RB_PX - 1);
        float n0 = 0.f, n1 = 0.f, n2 = 0.f, n3 = 0.f, n4 = 0.f, den = 0.f;
#pragma unroll
        for (int s = 0; s < NSHARD; ++s) {
            const float* b = acc + ((size_t)(rbin * NSHARD + s) * RB_PX + lr) * 6;
            n0 += b[0]; n1 += b[1]; n2 += b[2];
            n3 += b[3]; n4 += b[4]; den += b[5];
        }
        const float inv = 1.f / den;
        out[0 * (size_t)NPIX + p] = n0 * inv;
        out[1 * (size_t)NPIX + p] = n1 * inv;
        out[2 * (size_t)NPIX + p] = n2 * inv;
        out[3 * (size_t)NPIX + p] = n3 * inv;
        out[4 * (size_t)NPIX + p] = n4 * inv;
    }
}

// ---------------- fallback kernels (small workspace) ----------------

__global__ void bp_scatter_fb_kernel(const float* __restrict__ sino,
                                     const float* __restrict__ vals,
                                     const int*   __restrict__ rows,
                                     const int*   __restrict__ cols,
                                     float* __restrict__ acc) {
    const long long stride = (long long)gridDim.x * blockDim.x;
    for (long long i = (long long)blockIdx.x * blockDim.x + threadIdx.x;
         i < NNZ; i += stride) {
        const float v = vals[i];
        const int   r = rows[i];
        const int   c = cols[i];
        atomicAdd(acc + (size_t)BSZ * NPIX + r, v);
#pragma unroll
        for (int b = 0; b < BSZ; ++b)
            atomicAdd(acc + (size_t)b * NPIX + r, v * sino[(size_t)b * SINO + c]);
    }
}

__global__ void bp_divide_fb_kernel(const float* __restrict__ acc,
                                    float* __restrict__ out) {
    const int i = blockIdx.x * blockDim.x + threadIdx.x;
    if (i < BSZ * NPIX) {
        const int p = i % NPIX;
        out[i] = acc[i] / acc[(size_t)BSZ * NPIX + p];
    }
}

// ---------------- launch ----------------

extern "C" void kernel_launch(void* const* d_in, const int* in_sizes, int n_in,
                              void* d_out, int out_size, void* d_ws, size_t ws_size,
                              hipStream_t stream) {
    const float* sino = (const float*)d_in[0];
    const float* vals = (const float*)d_in[1];
    const int*   rows = (const int*)d_in[2];
    const int*   cols = (const int*)d_in[3];
    float* out = (float*)d_out;

    // workspace layout (bytes, all 16B-aligned) — identical to rounds 7/9:
    const size_t rec_b    = (size_t)NNZ * 8;
    const size_t sino_b_b = (size_t)SINO * 16;
    const size_t acc_b    = (size_t)NBIN * RB_PX * 6 * 4;
    const size_t cnt_b    = (size_t)SCAT_BLOCKS * NBIN * 4;
    const size_t need = rec_b + sino_b_b + acc_b + 2 * cnt_b + (size_t)(NBIN + NBIN + 1 + 8) * 4;

    if (ws_size >= need) {
        char* w = (char*)d_ws;
        unsigned long long* rec = (unsigned long long*)w;   w += rec_b;
        u32x4*    sinob  = (u32x4*)w;                       w += sino_b_b;
        float*    acc    = (float*)w;                       w += acc_b;
        unsigned* cnt    = (unsigned*)w;                    w += cnt_b;
        unsigned* base   = (unsigned*)w;                    w += cnt_b;
        unsigned* tot    = (unsigned*)w;                    w += (size_t)NBIN * 4;
        unsigned* binoff = (unsigned*)w;

        k_sino_bf16<<<(SINO + 255) / 256, 256, 0, stream>>>(sino, sinob);
        k_count<<<SCAT_BLOCKS, SCAT_THREADS, 0, stream>>>(rows, cols, cnt);
        k_tot<<<NBIN, SCAT_BLOCKS, 0, stream>>>(cnt, tot);
        k_scan<<<1, NBIN, 0, stream>>>(tot, binoff);
        k_base<<<NBIN, SCAT_BLOCKS, 0, stream>>>(cnt, binoff, base);
        k_scatter<<<SCAT_BLOCKS, SCAT_THREADS, 0, stream>>>(vals, rows, cols, base, rec);
        k_accum<<<NBIN, ACC_THREADS, 0, stream>>>((const f32x2*)rec, sinob, binoff, acc);
        k_reduce<<<(NPIX + 255) / 256, 256, 0, stream>>>(acc, out);
    } else {
        float* acc = (float*)d_ws;
        (void)hipMemsetAsync(acc, 0, (size_t)(BSZ + 1) * NPIX * sizeof(float), stream);
        bp_scatter_fb_kernel<<<2048, 256, 0, stream>>>(sino, vals, rows, cols, acc);
        bp_divide_fb_kernel<<<(BSZ * NPIX + 255) / 256, 256, 0, stream>>>(acc, out);
    }
}

// Round 12
// 412.429 us; speedup vs baseline: 1.0120x; 1.0066x over previous
//
#include <hip/hip_runtime.h>

#define BSZ  5
#define PROJ 1000
#define DET  513
#define IMG  362
#define NPIX (IMG * IMG)          // 131044
#define SINO (PROJ * DET)         // 513000
#define NNZ  20000000

#define NSHARD     4
#define SHARD_COLS (SINO / NSHARD)   // 128250
#define RB_SHIFT   10
#define RB_PX      1024
#define NRBIN      128
#define NBIN       (NRBIN * NSHARD)  // 512

#define SCAT_BLOCKS  256
#define SCAT_THREADS 1024
#define CHUNK        78128           // ceil(NNZ/256) rounded to mult of 16
#define TILE         4096

#define SC2_THREADS  512             // scatter: 512 thr -> 2 co-resident blocks/CU

#define ACC_THREADS  512

#define FXSCALE 262144.0f            // 2^18
#define FXINV   (1.0f / 262144.0f)
#define FXBIAS  4194304              // 2^22

typedef int      i32x4 __attribute__((ext_vector_type(4)));
typedef float    f32x4 __attribute__((ext_vector_type(4)));
typedef float    f32x2 __attribute__((ext_vector_type(2)));
typedef unsigned u32x4 __attribute__((ext_vector_type(4)));

// no-return LDS atomics (fire-and-forget).
__device__ __forceinline__ unsigned lds_off(const void* p) {
    return (unsigned)(size_t)p;
}
__device__ __forceinline__ void ds_add_u32_nr(unsigned off, unsigned v) {
    asm volatile("ds_add_u32 %0, %1" :: "v"(off), "v"(v) : "memory");
}
__device__ __forceinline__ void ds_add_u64_nr(unsigned off, unsigned long long v) {
    asm volatile("ds_add_u64 %0, %1" :: "v"(off), "v"(v) : "memory");
}
// per-wave drain: inline-asm DS ops COMPLETE before the following barrier.
__device__ __forceinline__ void lgkm_drain() {
    asm volatile("s_waitcnt lgkmcnt(0)" ::: "memory");
}

__device__ __forceinline__ int bin_of(int row, int col) {
    return ((row >> RB_SHIFT) << 2) | (col / SHARD_COLS);
}

// ---------------- fast path kernels ----------------

// sino -> bf16 packed table: [col] = u32x4 {b0|b1<<16, b2|b3<<16, b4, 0}
__global__ void k_sino_bf16(const float* __restrict__ sino, u32x4* __restrict__ sino_b) {
    const int c = blockIdx.x * blockDim.x + threadIdx.x;
    if (c < SINO) {
        unsigned b[5];
#pragma unroll
        for (int k = 0; k < 5; ++k) {
            const unsigned u = __float_as_uint(sino[(size_t)k * SINO + c]);
            b[k] = (u + 0x7FFFu + ((u >> 16) & 1u)) >> 16;   // RNE to bf16
        }
        u32x4 o;
        o.x = b[0] | (b[1] << 16);
        o.y = b[2] | (b[3] << 16);
        o.z = b[4];
        o.w = 0u;
        sino_b[c] = o;
    }
}

// pass A: per-(block,bin) exact counts
__global__ __launch_bounds__(SCAT_THREADS) void k_count(
        const int* __restrict__ rows, const int* __restrict__ cols,
        unsigned* __restrict__ cnt) {
    __shared__ unsigned c[NBIN];
    const int t = threadIdx.x;
    if (t < NBIN) c[t] = 0u;
    __syncthreads();
    const int lo = blockIdx.x * CHUNK;
    const int hi = (lo + CHUNK < NNZ) ? lo + CHUNK : NNZ;
    if (lo < hi) {
        for (int i4 = lo / 4 + t; i4 * 4 < hi; i4 += SCAT_THREADS) {
            const i32x4 r = __builtin_nontemporal_load(((const i32x4*)rows) + i4);
            const i32x4 q = __builtin_nontemporal_load(((const i32x4*)cols) + i4);
            ds_add_u32_nr(lds_off(&c[bin_of(r.x, q.x)]), 1u);
            ds_add_u32_nr(lds_off(&c[bin_of(r.y, q.y)]), 1u);
            ds_add_u32_nr(lds_off(&c[bin_of(r.z, q.z)]), 1u);
            ds_add_u32_nr(lds_off(&c[bin_of(r.w, q.w)]), 1u);
        }
    }
    lgkm_drain();
    __syncthreads();
    if (t < NBIN) cnt[(size_t)blockIdx.x * NBIN + t] = c[t];
}

// per-bin totals: block b reduces cnt[*][b]
__global__ __launch_bounds__(SCAT_BLOCKS) void k_tot(
        const unsigned* __restrict__ cnt, unsigned* __restrict__ tot) {
    __shared__ unsigned s[SCAT_BLOCKS];
    const int b = blockIdx.x, t = threadIdx.x;
    s[t] = cnt[(size_t)t * NBIN + b];
    __syncthreads();
    for (int o = SCAT_BLOCKS / 2; o > 0; o >>= 1) {
        if (t < o) s[t] += s[t + o];
        __syncthreads();
    }
    if (t == 0) tot[b] = s[0];
}

// exclusive scan of tot -> binoff
__global__ __launch_bounds__(NBIN) void k_scan(
        const unsigned* __restrict__ tot, unsigned* __restrict__ binoff) {
    __shared__ unsigned s[NBIN];
    const int t = threadIdx.x;
    const unsigned my = tot[t];
    s[t] = my;
    __syncthreads();
    for (int o = 1; o < NBIN; o <<= 1) {
        const unsigned v = (t >= o) ? s[t - o] : 0u;
        __syncthreads();
        s[t] += v;
        __syncthreads();
    }
    binoff[t] = s[t] - my;
    if (t == NBIN - 1) binoff[NBIN] = (unsigned)NNZ;
}

// per-(block,bin) global base positions
__global__ __launch_bounds__(SCAT_BLOCKS) void k_base(
        const unsigned* __restrict__ cnt, const unsigned* __restrict__ binoff,
        unsigned* __restrict__ base) {
    __shared__ unsigned s[SCAT_BLOCKS];
    const int b = blockIdx.x, t = threadIdx.x;
    const unsigned my = cnt[(size_t)t * NBIN + b];
    s[t] = my;
    __syncthreads();
    for (int o = 1; o < SCAT_BLOCKS; o <<= 1) {
        const unsigned v = (t >= o) ? s[t - o] : 0u;
        __syncthreads();
        s[t] += v;
        __syncthreads();
    }
    base[(size_t)t * NBIN + b] = binoff[b] + s[t] - my;
}

// pass B: tile-local counting sort, 512-thr co-resident blocks, pipelined tile loads
// LDS record: [63:55]=bin(9) [54:26]=packed(29)=lr(10)|col(19) [25:0]=val26
__global__ __launch_bounds__(SC2_THREADS) void k_scatter(
        const float* __restrict__ vals, const int* __restrict__ rows,
        const int* __restrict__ cols, const unsigned* __restrict__ base,
        unsigned long long* __restrict__ rec) {
    __shared__ unsigned cnt[NBIN];
    __shared__ unsigned toff[NBIN];
    __shared__ unsigned ebase[NBIN];
    __shared__ unsigned bs2[NBIN];
    __shared__ unsigned wsum[8];
    __shared__ unsigned long long sdata[TILE];   // 32 KB
    const int t = threadIdx.x;
    const int lane = t & 63;
    const int lo = blockIdx.x * CHUNK;
    const int hi = (lo + CHUNK < NNZ) ? lo + CHUNK : NNZ;
    if (lo >= hi) return;

    if (t < NBIN) { bs2[t] = base[(size_t)blockIdx.x * NBIN + t]; cnt[t] = 0u; }

    // stage tile 0 (8 records/thread)
    i32x4 sr0, sr1, sq0, sq1; f32x4 sv0, sv1;
    {
        const int n0 = (lo + TILE < hi) ? TILE : (hi - lo);
        if (t * 8 < n0) {
            const int i4 = (lo + t * 8) >> 2;
            sr0 = __builtin_nontemporal_load(((const i32x4*)rows) + i4);
            sr1 = __builtin_nontemporal_load(((const i32x4*)rows) + i4 + 1);
            sq0 = __builtin_nontemporal_load(((const i32x4*)cols) + i4);
            sq1 = __builtin_nontemporal_load(((const i32x4*)cols) + i4 + 1);
            sv0 = __builtin_nontemporal_load(((const f32x4*)vals) + i4);
            sv1 = __builtin_nontemporal_load(((const f32x4*)vals) + i4 + 1);
        }
    }
    __syncthreads();

    for (int tb = lo; tb < hi; tb += TILE) {
        const int n = (tb + TILE < hi) ? TILE : (hi - tb);   // mult of 16
        const bool act = (t * 8) < n;

        // current tile = staged regs
        const i32x4 cr0 = sr0, cr1 = sr1, cq0 = sq0, cq1 = sq1;
        const f32x4 cv0 = sv0, cv1 = sv1;

        // issue next-tile staging loads (overlap with this tile's phases)
        const int ntb = tb + TILE;
        if (ntb < hi) {
            const int nn = (ntb + TILE < hi) ? TILE : (hi - ntb);
            if (t * 8 < nn) {
                const int i4 = (ntb + t * 8) >> 2;
                sr0 = __builtin_nontemporal_load(((const i32x4*)rows) + i4);
                sr1 = __builtin_nontemporal_load(((const i32x4*)rows) + i4 + 1);
                sq0 = __builtin_nontemporal_load(((const i32x4*)cols) + i4);
                sq1 = __builtin_nontemporal_load(((const i32x4*)cols) + i4 + 1);
                sv0 = __builtin_nontemporal_load(((const f32x4*)vals) + i4);
                sv1 = __builtin_nontemporal_load(((const f32x4*)vals) + i4 + 1);
            }
        }

        // Phase B: claim slots (8 tracked rtn atomics), build packed records
        unsigned long long r8[8];
        unsigned sl[8];
        if (act) {
#pragma unroll
            for (int k = 0; k < 8; ++k) {
                const int rr = (k < 4) ? cr0[k] : cr1[k - 4];
                const int qq = (k < 4) ? cq0[k] : cq1[k - 4];
                const float vf = (k < 4) ? cv0[k] : cv1[k - 4];
                const unsigned bn = (unsigned)bin_of(rr, qq);
                const unsigned packed =
                    ((unsigned)(rr & (RB_PX - 1)) << 19) | (unsigned)qq;
                const unsigned v26 = __float_as_uint(vf) >> 6;
                r8[k] = ((unsigned long long)bn << 55)
                      | ((unsigned long long)packed << 26)
                      | (unsigned long long)v26;
                sl[k] = atomicAdd(&cnt[bn], 1u);
            }
        }
        __syncthreads();

        // Phase C: exclusive scan of cnt[512] via per-wave __shfl_up (8 waves),
        // fused cursor advance + counter reset
        unsigned x = 0u, incl = 0u;
        if (t < NBIN) {
            x = cnt[t];
            incl = x;
#pragma unroll
            for (int o = 1; o < 64; o <<= 1) {
                const unsigned y = __shfl_up(incl, (unsigned)o, 64);
                if (lane >= o) incl += y;
            }
            if (lane == 63) wsum[t >> 6] = incl;
        }
        __syncthreads();
        if (t < NBIN) {
            unsigned wo = 0u;
            const int w = t >> 6;
            for (int k = 0; k < w; ++k) wo += wsum[k];
            const unsigned e = wo + incl - x;        // exclusive prefix for bin t
            toff[t] = e;
            ebase[t] = bs2[t] - e;
            bs2[t] += x;                             // advance segment cursor
            cnt[t] = 0u;                             // reset for next tile
        }
        __syncthreads();

        // Phase D: place records sorted into LDS
        if (act) {
#pragma unroll
            for (int k = 0; k < 8; ++k) {
                const unsigned bn = (unsigned)(r8[k] >> 55);
                sdata[toff[bn] + sl[k]] = r8[k];
            }
        }
        __syncthreads();

        // Phase E: emission — consecutive threads -> consecutive addresses per bin-run
        for (int j = t; j < n; j += SC2_THREADS) {
            const unsigned long long u = sdata[j];
            const unsigned sb = (unsigned)(u >> 55);
            const unsigned packed = ((unsigned)(u >> 26)) & 0x1FFFFFFFu;
            const unsigned vbits = ((unsigned)u & 0x03FFFFFFu) << 6;
            __builtin_nontemporal_store(
                ((unsigned long long)packed << 32) | (unsigned long long)vbits,
                rec + ebase[sb] + (unsigned)j);
        }
        __syncthreads();
    }
}

// accumulate one bin in LDS with fixed-point packed u64 no-rtn atomics
__global__ __launch_bounds__(ACC_THREADS) void k_accum(
        const f32x2* __restrict__ rec, const u32x4* __restrict__ sino_b,
        const unsigned* __restrict__ binoff, float* __restrict__ acc) {
    __shared__ unsigned long long l8[RB_PX * 5];   // 40 KB
    const int t = threadIdx.x;
    for (int j = t; j < RB_PX * 5; j += ACC_THREADS) l8[j] = 0ull;
    __syncthreads();
    const int bin = blockIdx.x;
    const unsigned lo = binoff[bin], hi = binoff[bin + 1];
    for (unsigned i = lo + t; i < hi; i += ACC_THREADS) {
        const f32x2 rc = __builtin_nontemporal_load(rec + i);
        const unsigned u = __float_as_uint(rc.y);
        const int col = (int)(u & 0x7FFFFu);
        const int lr  = (int)(u >> 19);
        const u32x4 sv = sino_b[col];
        const float v = rc.x;
        const int q0 = __float2int_rn(v * __uint_as_float(sv.x << 16)         * FXSCALE);
        const int q1 = __float2int_rn(v * __uint_as_float(sv.x & 0xFFFF0000u) * FXSCALE);
        const int q2 = __float2int_rn(v * __uint_as_float(sv.y << 16)         * FXSCALE);
        const int q3 = __float2int_rn(v * __uint_as_float(sv.y & 0xFFFF0000u) * FXSCALE);
        const int q4 = __float2int_rn(v * __uint_as_float(sv.z << 16)         * FXSCALE);
        const int q5 = __float2int_rn(v * FXSCALE);
        const unsigned b = lds_off(&l8[(unsigned)lr * 5u]);
        ds_add_u64_nr(b,
            ((unsigned long long)(unsigned)q1 << 32) | (unsigned)(q0 + FXBIAS));
        ds_add_u64_nr(b + 8,
            ((unsigned long long)(unsigned)q3 << 32) | (unsigned)(q2 + FXBIAS));
        ds_add_u64_nr(b + 16,
            ((unsigned long long)(unsigned)q5 << 32) | (unsigned)(q4 + FXBIAS));
        ds_add_u32_nr(b + 24, 1u);
    }
    lgkm_drain();
    __syncthreads();
    float* dst = acc + (size_t)bin * (RB_PX * 6);
    for (int px = t; px < RB_PX; px += ACC_THREADS) {
        const unsigned long long a0 = l8[px * 5 + 0];
        const unsigned long long a1 = l8[px * 5 + 1];
        const unsigned long long a2 = l8[px * 5 + 2];
        const unsigned n = (unsigned)(l8[px * 5 + 3] & 0xFFFFFFFFull);
        const long long nb = (long long)n * FXBIAS;
        float* d = dst + px * 6;
        d[0] = (float)((long long)(unsigned)(a0 & 0xFFFFFFFFull) - nb) * FXINV;
        d[1] = (float)((int)(a0 >> 32)) * FXINV;
        d[2] = (float)((long long)(unsigned)(a1 & 0xFFFFFFFFull) - nb) * FXINV;
        d[3] = (float)((int)(a1 >> 32)) * FXINV;
        d[4] = (float)((long long)(unsigned)(a2 & 0xFFFFFFFFull) - nb) * FXINV;
        d[5] = (float)((int)(a2 >> 32)) * FXINV;
    }
}

// sum 4 shards per pixel, divide, write [BSZ][NPIX]
__global__ void k_reduce(const float* __restrict__ acc, float* __restrict__ out) {
    const int p = blockIdx.x * blockDim.x + threadIdx.x;
    if (p < NPIX) {
        const int rbin = p >> RB_SHIFT, lr = p & (RB_PX - 1);
        float n0 = 0.f, n1 = 0.f, n2 = 0.f, n3 = 0.f, n4 = 0.f, den = 0.f;
#pragma unroll
        for (int s = 0; s < NSHARD; ++s) {
            const float* b = acc + ((size_t)(rbin * NSHARD + s) * RB_PX + lr) * 6;
            n0 += b[0]; n1 += b[1]; n2 += b[2];
            n3 += b[3]; n4 += b[4]; den += b[5];
        }
        const float inv = 1.f / den;
        out[0 * (size_t)NPIX + p] = n0 * inv;
        out[1 * (size_t)NPIX + p] = n1 * inv;
        out[2 * (size_t)NPIX + p] = n2 * inv;
        out[3 * (size_t)NPIX + p] = n3 * inv;
        out[4 * (size_t)NPIX + p] = n4 * inv;
    }
}

// ---------------- fallback kernels (small workspace) ----------------

__global__ void bp_scatter_fb_kernel(const float* __restrict__ sino,
                                     const float* __restrict__ vals,
                                     const int*   __restrict__ rows,
                                     const int*   __restrict__ cols,
                                     float* __restrict__ acc) {
    const long long stride = (long long)gridDim.x * blockDim.x;
    for (long long i = (long long)blockIdx.x * blockDim.x + threadIdx.x;
         i < NNZ; i += stride) {
        const float v = vals[i];
        const int   r = rows[i];
        const int   c = cols[i];
        atomicAdd(acc + (size_t)BSZ * NPIX + r, v);
#pragma unroll
        for (int b = 0; b < BSZ; ++b)
            atomicAdd(acc + (size_t)b * NPIX + r, v * sino[(size_t)b * SINO + c]);
    }
}

__global__ void bp_divide_fb_kernel(const float* __restrict__ acc,
                                    float* __restrict__ out) {
    const int i = blockIdx.x * blockDim.x + threadIdx.x;
    if (i < BSZ * NPIX) {
        const int p = i % NPIX;
        out[i] = acc[i] / acc[(size_t)BSZ * NPIX + p];
    }
}

// ---------------- launch ----------------

extern "C" void kernel_launch(void* const* d_in, const int* in_sizes, int n_in,
                              void* d_out, int out_size, void* d_ws, size_t ws_size,
                              hipStream_t stream) {
    const float* sino = (const float*)d_in[0];
    const float* vals = (const float*)d_in[1];
    const int*   rows = (const int*)d_in[2];
    const int*   cols = (const int*)d_in[3];
    float* out = (float*)d_out;

    // workspace layout (bytes, all 16B-aligned) — identical to rounds 7/9/11:
    const size_t rec_b    = (size_t)NNZ * 8;
    const size_t sino_b_b = (size_t)SINO * 16;
    const size_t acc_b    = (size_t)NBIN * RB_PX * 6 * 4;
    const size_t cnt_b    = (size_t)SCAT_BLOCKS * NBIN * 4;
    const size_t need = rec_b + sino_b_b + acc_b + 2 * cnt_b + (size_t)(NBIN + NBIN + 1 + 8) * 4;

    if (ws_size >= need) {
        char* w = (char*)d_ws;
        unsigned long long* rec = (unsigned long long*)w;   w += rec_b;
        u32x4*    sinob  = (u32x4*)w;                       w += sino_b_b;
        float*    acc    = (float*)w;                       w += acc_b;
        unsigned* cnt    = (unsigned*)w;                    w += cnt_b;
        unsigned* base   = (unsigned*)w;                    w += cnt_b;
        unsigned* tot    = (unsigned*)w;                    w += (size_t)NBIN * 4;
        unsigned* binoff = (unsigned*)w;

        k_sino_bf16<<<(SINO + 255) / 256, 256, 0, stream>>>(sino, sinob);
        k_count<<<SCAT_BLOCKS, SCAT_THREADS, 0, stream>>>(rows, cols, cnt);
        k_tot<<<NBIN, SCAT_BLOCKS, 0, stream>>>(cnt, tot);
        k_scan<<<1, NBIN, 0, stream>>>(tot, binoff);
        k_base<<<NBIN, SCAT_BLOCKS, 0, stream>>>(cnt, binoff, base);
        k_scatter<<<SCAT_BLOCKS, SC2_THREADS, 0, stream>>>(vals, rows, cols, base, rec);
        k_accum<<<NBIN, ACC_THREADS, 0, stream>>>((const f32x2*)rec, sinob, binoff, acc);
        k_reduce<<<(NPIX + 255) / 256, 256, 0, stream>>>(acc, out);
    } else {
        float* acc = (float*)d_ws;
        (void)hipMemsetAsync(acc, 0, (size_t)(BSZ + 1) * NPIX * sizeof(float), stream);
        bp_scatter_fb_kernel<<<2048, 256, 0, stream>>>(sino, vals, rows, cols, acc);
        bp_divide_fb_kernel<<<(BSZ * NPIX + 255) / 256, 256, 0, stream>>>(acc, out);
    }
}

// Round 13
// 281.649 us; speedup vs baseline: 1.4819x; 1.4643x over previous
//
#include <hip/hip_runtime.h>
#include <hip/hip_fp16.h>

#define BSZ  5
#define PROJ 1000
#define DET  513
#define IMG  362
#define NPIX (IMG * IMG)          // 131044
#define SINO (PROJ * DET)         // 513000
#define NNZ  20000000

#define NSHARD     4
#define SHARD_COLS (SINO / NSHARD)   // 128250
#define RB_SHIFT   10
#define RB_PX      1024
#define NRBIN      128
#define NBIN       (NRBIN * NSHARD)  // 512

#define SCAT_BLOCKS  256
#define SCAT_THREADS 1024
#define CHUNK        78128           // ceil(NNZ/256) rounded to mult of 16
#define TILE         4096

#define SC2_THREADS  512

#define ACC_THREADS  512

// fixed-point: scale 2^14, bias 2^18, n-tag 2^24 in slot-3 high
#define FXSCALE 16384.0f
#define FXINV   (1.0f / 16384.0f)
#define FXB     262144               // 2^18
#define NTAG    0x1000000u           // 2^24

typedef int      i32x4 __attribute__((ext_vector_type(4)));
typedef float    f32x4 __attribute__((ext_vector_type(4)));
typedef unsigned u32x4 __attribute__((ext_vector_type(4)));

// no-return LDS atomics (fire-and-forget).
__device__ __forceinline__ unsigned lds_off(const void* p) {
    return (unsigned)(size_t)p;
}
__device__ __forceinline__ void ds_add_u32_nr(unsigned off, unsigned v) {
    asm volatile("ds_add_u32 %0, %1" :: "v"(off), "v"(v) : "memory");
}
__device__ __forceinline__ void ds_add_u64_nr(unsigned off, unsigned long long v) {
    asm volatile("ds_add_u64 %0, %1" :: "v"(off), "v"(v) : "memory");
}
// per-wave drain: inline-asm DS ops COMPLETE before the following barrier.
__device__ __forceinline__ void lgkm_drain() {
    asm volatile("s_waitcnt lgkmcnt(0)" ::: "memory");
}

__device__ __forceinline__ int bin_of(int row, int col) {
    return ((row >> RB_SHIFT) << 2) | (col / SHARD_COLS);
}

// ---------------- fast path kernels ----------------

// sino -> bf16 packed table: [col] = u32x4 {b0|b1<<16, b2|b3<<16, b4, 0}
__global__ void k_sino_bf16(const float* __restrict__ sino, u32x4* __restrict__ sino_b) {
    const int c = blockIdx.x * blockDim.x + threadIdx.x;
    if (c < SINO) {
        unsigned b[5];
#pragma unroll
        for (int k = 0; k < 5; ++k) {
            const unsigned u = __float_as_uint(sino[(size_t)k * SINO + c]);
            b[k] = (u + 0x7FFFu + ((u >> 16) & 1u)) >> 16;   // RNE to bf16
        }
        u32x4 o;
        o.x = b[0] | (b[1] << 16);
        o.y = b[2] | (b[3] << 16);
        o.z = b[4];
        o.w = 0u;
        sino_b[c] = o;
    }
}

// pass A: per-(block,bin) exact counts
__global__ __launch_bounds__(SCAT_THREADS) void k_count(
        const int* __restrict__ rows, const int* __restrict__ cols,
        unsigned* __restrict__ cnt) {
    __shared__ unsigned c[NBIN];
    const int t = threadIdx.x;
    if (t < NBIN) c[t] = 0u;
    __syncthreads();
    const int lo = blockIdx.x * CHUNK;
    const int hi = (lo + CHUNK < NNZ) ? lo + CHUNK : NNZ;
    if (lo < hi) {
        for (int i4 = lo / 4 + t; i4 * 4 < hi; i4 += SCAT_THREADS) {
            const i32x4 r = __builtin_nontemporal_load(((const i32x4*)rows) + i4);
            const i32x4 q = __builtin_nontemporal_load(((const i32x4*)cols) + i4);
            ds_add_u32_nr(lds_off(&c[bin_of(r.x, q.x)]), 1u);
            ds_add_u32_nr(lds_off(&c[bin_of(r.y, q.y)]), 1u);
            ds_add_u32_nr(lds_off(&c[bin_of(r.z, q.z)]), 1u);
            ds_add_u32_nr(lds_off(&c[bin_of(r.w, q.w)]), 1u);
        }
    }
    lgkm_drain();
    __syncthreads();
    if (t < NBIN) cnt[(size_t)blockIdx.x * NBIN + t] = c[t];
}

// per-bin totals: block b reduces cnt[*][b]
__global__ __launch_bounds__(SCAT_BLOCKS) void k_tot(
        const unsigned* __restrict__ cnt, unsigned* __restrict__ tot) {
    __shared__ unsigned s[SCAT_BLOCKS];
    const int b = blockIdx.x, t = threadIdx.x;
    s[t] = cnt[(size_t)t * NBIN + b];
    __syncthreads();
    for (int o = SCAT_BLOCKS / 2; o > 0; o >>= 1) {
        if (t < o) s[t] += s[t + o];
        __syncthreads();
    }
    if (t == 0) tot[b] = s[0];
}

// exclusive scan of tot -> binoff
__global__ __launch_bounds__(NBIN) void k_scan(
        const unsigned* __restrict__ tot, unsigned* __restrict__ binoff) {
    __shared__ unsigned s[NBIN];
    const int t = threadIdx.x;
    const unsigned my = tot[t];
    s[t] = my;
    __syncthreads();
    for (int o = 1; o < NBIN; o <<= 1) {
        const unsigned v = (t >= o) ? s[t - o] : 0u;
        __syncthreads();
        s[t] += v;
        __syncthreads();
    }
    binoff[t] = s[t] - my;
    if (t == NBIN - 1) binoff[NBIN] = (unsigned)NNZ;
}

// per-(block,bin) global base positions
__global__ __launch_bounds__(SCAT_BLOCKS) void k_base(
        const unsigned* __restrict__ cnt, const unsigned* __restrict__ binoff,
        unsigned* __restrict__ base) {
    __shared__ unsigned s[SCAT_BLOCKS];
    const int b = blockIdx.x, t = threadIdx.x;
    const unsigned my = cnt[(size_t)t * NBIN + b];
    s[t] = my;
    __syncthreads();
    for (int o = 1; o < SCAT_BLOCKS; o <<= 1) {
        const unsigned v = (t >= o) ? s[t - o] : 0u;
        __syncthreads();
        s[t] += v;
        __syncthreads();
    }
    base[(size_t)t * NBIN + b] = binoff[b] + s[t] - my;
}

// pass B: tile-local counting sort, SoA 6B records, L2-combinable emission
// LDS record: [63:55]=bin(9) [54:45]=lr(10) [44:26]=col(19) [15:0]=fp16 val
__global__ __launch_bounds__(SC2_THREADS) void k_scatter(
        const float* __restrict__ vals, const int* __restrict__ rows,
        const int* __restrict__ cols, const unsigned* __restrict__ base,
        unsigned* __restrict__ recA, unsigned short* __restrict__ recB) {
    __shared__ unsigned cnt[NBIN];
    __shared__ unsigned toff[NBIN];
    __shared__ unsigned ebase[NBIN];
    __shared__ unsigned bs2[NBIN];
    __shared__ unsigned wsum[8];
    __shared__ unsigned long long sdata[TILE];   // 32 KB
    const int t = threadIdx.x;
    const int lane = t & 63;
    const int lo = blockIdx.x * CHUNK;
    const int hi = (lo + CHUNK < NNZ) ? lo + CHUNK : NNZ;
    if (lo >= hi) return;

    if (t < NBIN) { bs2[t] = base[(size_t)blockIdx.x * NBIN + t]; cnt[t] = 0u; }

    // stage tile 0 (8 records/thread)
    i32x4 sr0, sr1, sq0, sq1; f32x4 sv0, sv1;
    {
        const int n0 = (lo + TILE < hi) ? TILE : (hi - lo);
        if (t * 8 < n0) {
            const int i4 = (lo + t * 8) >> 2;
            sr0 = __builtin_nontemporal_load(((const i32x4*)rows) + i4);
            sr1 = __builtin_nontemporal_load(((const i32x4*)rows) + i4 + 1);
            sq0 = __builtin_nontemporal_load(((const i32x4*)cols) + i4);
            sq1 = __builtin_nontemporal_load(((const i32x4*)cols) + i4 + 1);
            sv0 = __builtin_nontemporal_load(((const f32x4*)vals) + i4);
            sv1 = __builtin_nontemporal_load(((const f32x4*)vals) + i4 + 1);
        }
    }
    __syncthreads();

    for (int tb = lo; tb < hi; tb += TILE) {
        const int n = (tb + TILE < hi) ? TILE : (hi - tb);   // mult of 16
        const bool act = (t * 8) < n;

        const i32x4 cr0 = sr0, cr1 = sr1, cq0 = sq0, cq1 = sq1;
        const f32x4 cv0 = sv0, cv1 = sv1;

        // issue next-tile staging loads (overlap with this tile's phases)
        const int ntb = tb + TILE;
        if (ntb < hi) {
            const int nn = (ntb + TILE < hi) ? TILE : (hi - ntb);
            if (t * 8 < nn) {
                const int i4 = (ntb + t * 8) >> 2;
                sr0 = __builtin_nontemporal_load(((const i32x4*)rows) + i4);
                sr1 = __builtin_nontemporal_load(((const i32x4*)rows) + i4 + 1);
                sq0 = __builtin_nontemporal_load(((const i32x4*)cols) + i4);
                sq1 = __builtin_nontemporal_load(((const i32x4*)cols) + i4 + 1);
                sv0 = __builtin_nontemporal_load(((const f32x4*)vals) + i4);
                sv1 = __builtin_nontemporal_load(((const f32x4*)vals) + i4 + 1);
            }
        }

        // Phase B: claim slots (8 tracked rtn atomics), build packed records
        unsigned long long r8[8];
        unsigned sl[8];
        if (act) {
#pragma unroll
            for (int k = 0; k < 8; ++k) {
                const int rr = (k < 4) ? cr0[k] : cr1[k - 4];
                const int qq = (k < 4) ? cq0[k] : cq1[k - 4];
                const float vf = (k < 4) ? cv0[k] : cv1[k - 4];
                const unsigned bn = (unsigned)bin_of(rr, qq);
                const unsigned vh = (unsigned)__half_as_ushort(__float2half(vf));
                r8[k] = ((unsigned long long)bn << 55)
                      | ((unsigned long long)(unsigned)(rr & (RB_PX - 1)) << 45)
                      | ((unsigned long long)(unsigned)qq << 26)
                      | (unsigned long long)vh;
                sl[k] = atomicAdd(&cnt[bn], 1u);
            }
        }
        __syncthreads();

        // Phase C: exclusive scan of cnt[512] via per-wave __shfl_up (8 waves),
        // fused cursor advance + counter reset
        unsigned x = 0u, incl = 0u;
        if (t < NBIN) {
            x = cnt[t];
            incl = x;
#pragma unroll
            for (int o = 1; o < 64; o <<= 1) {
                const unsigned y = __shfl_up(incl, (unsigned)o, 64);
                if (lane >= o) incl += y;
            }
            if (lane == 63) wsum[t >> 6] = incl;
        }
        __syncthreads();
        if (t < NBIN) {
            unsigned wo = 0u;
            const int w = t >> 6;
            for (int k = 0; k < w; ++k) wo += wsum[k];
            const unsigned e = wo + incl - x;        // exclusive prefix for bin t
            toff[t] = e;
            ebase[t] = bs2[t] - e;
            bs2[t] += x;
            cnt[t] = 0u;
        }
        __syncthreads();

        // Phase D: place records sorted into LDS
        if (act) {
#pragma unroll
            for (int k = 0; k < 8; ++k) {
                const unsigned bn = (unsigned)(r8[k] >> 55);
                sdata[toff[bn] + sl[k]] = r8[k];
            }
        }
        __syncthreads();

        // Phase E: emission — plain stores (L2 write-combines across tiles)
        for (int j = t; j < n; j += SC2_THREADS) {
            const unsigned long long u = sdata[j];
            const unsigned sb = (unsigned)(u >> 55);
            const unsigned pos = ebase[sb] + (unsigned)j;
            recA[pos] = (unsigned)((u >> 26) & 0x1FFFFFFFu);   // {lr:10|col:19}
            recB[pos] = (unsigned short)(u & 0xFFFFu);         // fp16 val
        }
        __syncthreads();
    }
}

// accumulate one bin in LDS: 3 fixed-point packed u64 no-rtn atomics per record
// per pixel: 3 u64: #1={q1 : q0+B} #2={q3 : q2+B} #3={q5+NTAG : q4+B}
__global__ __launch_bounds__(ACC_THREADS) void k_accum(
        const unsigned* __restrict__ recA, const unsigned short* __restrict__ recB,
        const u32x4* __restrict__ sino_b,
        const unsigned* __restrict__ binoff, float* __restrict__ acc) {
    __shared__ unsigned long long l8[RB_PX * 3];   // 24 KB
    const int t = threadIdx.x;
    for (int j = t; j < RB_PX * 3; j += ACC_THREADS) l8[j] = 0ull;
    __syncthreads();
    const int bin = blockIdx.x;
    const unsigned lo = binoff[bin], hi = binoff[bin + 1];
    for (unsigned i = lo + t; i < hi; i += ACC_THREADS) {
        const unsigned a = __builtin_nontemporal_load(recA + i);
        const unsigned short hraw = recB[i];
        const float v = __half2float(__ushort_as_half(hraw));
        const int col = (int)(a & 0x7FFFFu);
        const int lr  = (int)(a >> 19);
        const u32x4 sv = sino_b[col];
        const int q0 = __float2int_rn(v * __uint_as_float(sv.x << 16)         * FXSCALE);
        const int q1 = __float2int_rn(v * __uint_as_float(sv.x & 0xFFFF0000u) * FXSCALE);
        const int q2 = __float2int_rn(v * __uint_as_float(sv.y << 16)         * FXSCALE);
        const int q3 = __float2int_rn(v * __uint_as_float(sv.y & 0xFFFF0000u) * FXSCALE);
        const int q4 = __float2int_rn(v * __uint_as_float(sv.z << 16)         * FXSCALE);
        const int q5 = __float2int_rn(v * FXSCALE);
        const unsigned b = lds_off(&l8[(unsigned)lr * 3u]);
        ds_add_u64_nr(b,
            ((unsigned long long)(unsigned)q1 << 32) | (unsigned)(q0 + FXB));
        ds_add_u64_nr(b + 8,
            ((unsigned long long)(unsigned)q3 << 32) | (unsigned)(q2 + FXB));
        ds_add_u64_nr(b + 16,
            ((unsigned long long)((unsigned)q5 + NTAG) << 32) | (unsigned)(q4 + FXB));
    }
    lgkm_drain();
    __syncthreads();
    float* dst = acc + (size_t)bin * (RB_PX * 6);
    for (int px = t; px < RB_PX; px += ACC_THREADS) {
        const unsigned long long a0 = l8[px * 3 + 0];
        const unsigned long long a1 = l8[px * 3 + 1];
        const unsigned long long a2 = l8[px * 3 + 2];
        const unsigned hi3 = (unsigned)(a2 >> 32);
        const unsigned n = hi3 >> 24;                     // record count
        const long long nb = (long long)n * FXB;
        float* d = dst + px * 6;
        d[0] = (float)((long long)(unsigned)(a0 & 0xFFFFFFFFull) - nb) * FXINV;
        d[1] = (float)((int)(a0 >> 32)) * FXINV;
        d[2] = (float)((long long)(unsigned)(a1 & 0xFFFFFFFFull) - nb) * FXINV;
        d[3] = (float)((int)(a1 >> 32)) * FXINV;
        d[4] = (float)((long long)(unsigned)(a2 & 0xFFFFFFFFull) - nb) * FXINV;
        d[5] = (float)(hi3 & 0xFFFFFFu) * FXINV;          // sum of vals (positive)
    }
}

// sum 4 shards per pixel, divide, write [BSZ][NPIX]
__global__ void k_reduce(const float* __restrict__ acc, float* __restrict__ out) {
    const int p = blockIdx.x * blockDim.x + threadIdx.x;
    if (p < NPIX) {
        const int rbin = p >> RB_SHIFT, lr = p & (RB_PX - 1);
        float n0 = 0.f, n1 = 0.f, n2 = 0.f, n3 = 0.f, n4 = 0.f, den = 0.f;
#pragma unroll
        for (int s = 0; s < NSHARD; ++s) {
            const float* b = acc + ((size_t)(rbin * NSHARD + s) * RB_PX + lr) * 6;
            n0 += b[0]; n1 += b[1]; n2 += b[2];
            n3 += b[3]; n4 += b[4]; den += b[5];
        }
        const float inv = 1.f / den;
        out[0 * (size_t)NPIX + p] = n0 * inv;
        out[1 * (size_t)NPIX + p] = n1 * inv;
        out[2 * (size_t)NPIX + p] = n2 * inv;
        out[3 * (size_t)NPIX + p] = n3 * inv;
        out[4 * (size_t)NPIX + p] = n4 * inv;
    }
}

// ---------------- fallback kernels (small workspace) ----------------

__global__ void bp_scatter_fb_kernel(const float* __restrict__ sino,
                                     const float* __restrict__ vals,
                                     const int*   __restrict__ rows,
                                     const int*   __restrict__ cols,
                                     float* __restrict__ acc) {
    const long long stride = (long long)gridDim.x * blockDim.x;
    for (long long i = (long long)blockIdx.x * blockDim.x + threadIdx.x;
         i < NNZ; i += stride) {
        const float v = vals[i];
        const int   r = rows[i];
        const int   c = cols[i];
        atomicAdd(acc + (size_t)BSZ * NPIX + r, v);
#pragma unroll
        for (int b = 0; b < BSZ; ++b)
            atomicAdd(acc + (size_t)b * NPIX + r, v * sino[(size_t)b * SINO + c]);
    }
}

__global__ void bp_divide_fb_kernel(const float* __restrict__ acc,
                                    float* __restrict__ out) {
    const int i = blockIdx.x * blockDim.x + threadIdx.x;
    if (i < BSZ * NPIX) {
        const int p = i % NPIX;
        out[i] = acc[i] / acc[(size_t)BSZ * NPIX + p];
    }
}

// ---------------- launch ----------------

extern "C" void kernel_launch(void* const* d_in, const int* in_sizes, int n_in,
                              void* d_out, int out_size, void* d_ws, size_t ws_size,
                              hipStream_t stream) {
    const float* sino = (const float*)d_in[0];
    const float* vals = (const float*)d_in[1];
    const int*   rows = (const int*)d_in[2];
    const int*   cols = (const int*)d_in[3];
    float* out = (float*)d_out;

    // workspace layout (bytes, all 16B-aligned):
    //   recA   : NNZ * 4                  =  80,000,000
    //   recB   : NNZ * 2                  =  40,000,000
    //   sino_b : SINO * 16                =   8,208,000
    //   acc    : NBIN * RB_PX * 6 * 4     =  12,582,912
    //   cnt    : SCAT_BLOCKS * NBIN * 4   =     524,288
    //   base   : SCAT_BLOCKS * NBIN * 4   =     524,288
    //   tot/binoff : small
    //   total ~ 141.8 MB (< proven bound)
    const size_t recA_b   = (size_t)NNZ * 4;
    const size_t recB_b   = (size_t)NNZ * 2;
    const size_t sino_b_b = (size_t)SINO * 16;
    const size_t acc_b    = (size_t)NBIN * RB_PX * 6 * 4;
    const size_t cnt_b    = (size_t)SCAT_BLOCKS * NBIN * 4;
    const size_t need = recA_b + recB_b + sino_b_b + acc_b + 2 * cnt_b
                      + (size_t)(NBIN + NBIN + 1 + 8) * 4;

    if (ws_size >= need) {
        char* w = (char*)d_ws;
        unsigned*       recA = (unsigned*)w;                w += recA_b;
        unsigned short* recB = (unsigned short*)w;          w += recB_b;
        u32x4*    sinob  = (u32x4*)w;                       w += sino_b_b;
        float*    acc    = (float*)w;                       w += acc_b;
        unsigned* cnt    = (unsigned*)w;                    w += cnt_b;
        unsigned* base   = (unsigned*)w;                    w += cnt_b;
        unsigned* tot    = (unsigned*)w;                    w += (size_t)NBIN * 4;
        unsigned* binoff = (unsigned*)w;

        k_sino_bf16<<<(SINO + 255) / 256, 256, 0, stream>>>(sino, sinob);
        k_count<<<SCAT_BLOCKS, SCAT_THREADS, 0, stream>>>(rows, cols, cnt);
        k_tot<<<NBIN, SCAT_BLOCKS, 0, stream>>>(cnt, tot);
        k_scan<<<1, NBIN, 0, stream>>>(tot, binoff);
        k_base<<<NBIN, SCAT_BLOCKS, 0, stream>>>(cnt, binoff, base);
        k_scatter<<<SCAT_BLOCKS, SC2_THREADS, 0, stream>>>(vals, rows, cols, base, recA, recB);
        k_accum<<<NBIN, ACC_THREADS, 0, stream>>>(recA, recB, sinob, binoff, acc);
        k_reduce<<<(NPIX + 255) / 256, 256, 0, stream>>>(acc, out);
    } else {
        float* acc = (float*)d_ws;
        (void)hipMemsetAsync(acc, 0, (size_t)(BSZ + 1) * NPIX * sizeof(float), stream);
        bp_scatter_fb_kernel<<<2048, 256, 0, stream>>>(sino, vals, rows, cols, acc);
        bp_divide_fb_kernel<<<(BSZ * NPIX + 255) / 256, 256, 0, stream>>>(acc, out);
    }
}

// Round 14
// 250.262 us; speedup vs baseline: 1.6677x; 1.1254x over previous
//
#include <hip/hip_runtime.h>
#include <hip/hip_fp16.h>

#define BSZ  5
#define PROJ 1000
#define DET  513
#define IMG  362
#define NPIX (IMG * IMG)          // 131044
#define SINO (PROJ * DET)         // 513000
#define NNZ  20000000

#define NSHARD     4
#define SHARD_COLS (SINO / NSHARD)   // 128250
#define RB_SHIFT   10
#define RB_PX      1024
#define NRBIN      128
#define NBIN       (NRBIN * NSHARD)  // 512

#define SCAT_BLOCKS  256
#define CHUNK        78128           // ceil(NNZ/256) rounded to mult of 16
#define TILE         4096
#define SC2_THREADS  512

#define CAP        200               // slots per (block,bin) cell; lambda=152.6, 3.8 sigma
#define OVF_CAP    65536

#define ACC_THREADS  512

// fixed-point: scale 2^14, bias 2^18, n-tag 2^24 in slot-3 high
#define FXSCALE 16384.0f
#define FXINV   (1.0f / 16384.0f)
#define FXB     262144               // 2^18
#define NTAG    0x1000000u           // 2^24

typedef int      i32x4 __attribute__((ext_vector_type(4)));
typedef float    f32x4 __attribute__((ext_vector_type(4)));
typedef unsigned u32x4 __attribute__((ext_vector_type(4)));

// no-return LDS atomics (fire-and-forget).
__device__ __forceinline__ unsigned lds_off(const void* p) {
    return (unsigned)(size_t)p;
}
__device__ __forceinline__ void ds_add_u64_nr(unsigned off, unsigned long long v) {
    asm volatile("ds_add_u64 %0, %1" :: "v"(off), "v"(v) : "memory");
}
// per-wave drain: inline-asm DS ops COMPLETE before the following barrier.
__device__ __forceinline__ void lgkm_drain() {
    asm volatile("s_waitcnt lgkmcnt(0)" ::: "memory");
}

__device__ __forceinline__ int bin_of(int row, int col) {
    return ((row >> RB_SHIFT) << 2) | (col / SHARD_COLS);
}

// ---------------- fast path kernels ----------------

// sino -> bf16 packed table: [col] = u32x4 {b0|b1<<16, b2|b3<<16, b4, 0}
__global__ void k_sino_bf16(const float* __restrict__ sino, u32x4* __restrict__ sino_b) {
    const int c = blockIdx.x * blockDim.x + threadIdx.x;
    if (c < SINO) {
        unsigned b[5];
#pragma unroll
        for (int k = 0; k < 5; ++k) {
            const unsigned u = __float_as_uint(sino[(size_t)k * SINO + c]);
            b[k] = (u + 0x7FFFu + ((u >> 16) & 1u)) >> 16;   // RNE to bf16
        }
        u32x4 o;
        o.x = b[0] | (b[1] << 16);
        o.y = b[2] | (b[3] << 16);
        o.z = b[4];
        o.w = 0u;
        sino_b[c] = o;
    }
}

// single pass: tile-local counting sort into fixed-capacity per-(block,bin) cells
// LDS record: [63:55]=bin(9) [54:45]=lr(10) [44:26]=col(19) [15:0]=fp16 val
__global__ __launch_bounds__(SC2_THREADS) void k_scatter(
        const float* __restrict__ vals, const int* __restrict__ rows,
        const int* __restrict__ cols,
        unsigned* __restrict__ recA, unsigned short* __restrict__ recB,
        unsigned* __restrict__ gcnt,
        unsigned long long* __restrict__ ovf, unsigned* __restrict__ ovf_n) {
    __shared__ unsigned cnt[NBIN];
    __shared__ unsigned toff[NBIN];
    __shared__ unsigned ebase[NBIN];
    __shared__ unsigned bs2[NBIN];
    __shared__ unsigned wsum[8];
    __shared__ unsigned long long sdata[TILE];   // 32 KB
    const int t = threadIdx.x;
    const int lane = t & 63;
    const int lo = blockIdx.x * CHUNK;
    const int hi = (lo + CHUNK < NNZ) ? lo + CHUNK : NNZ;
    if (lo >= hi) return;

    if (t < NBIN) {
        bs2[t] = ((unsigned)blockIdx.x * NBIN + (unsigned)t) * CAP;  // cell base
        cnt[t] = 0u;
    }

    // stage tile 0 (8 records/thread)
    i32x4 sr0, sr1, sq0, sq1; f32x4 sv0, sv1;
    {
        const int n0 = (lo + TILE < hi) ? TILE : (hi - lo);
        if (t * 8 < n0) {
            const int i4 = (lo + t * 8) >> 2;
            sr0 = __builtin_nontemporal_load(((const i32x4*)rows) + i4);
            sr1 = __builtin_nontemporal_load(((const i32x4*)rows) + i4 + 1);
            sq0 = __builtin_nontemporal_load(((const i32x4*)cols) + i4);
            sq1 = __builtin_nontemporal_load(((const i32x4*)cols) + i4 + 1);
            sv0 = __builtin_nontemporal_load(((const f32x4*)vals) + i4);
            sv1 = __builtin_nontemporal_load(((const f32x4*)vals) + i4 + 1);
        }
    }
    __syncthreads();

    for (int tb = lo; tb < hi; tb += TILE) {
        const int n = (tb + TILE < hi) ? TILE : (hi - tb);   // mult of 16
        const bool act = (t * 8) < n;

        const i32x4 cr0 = sr0, cr1 = sr1, cq0 = sq0, cq1 = sq1;
        const f32x4 cv0 = sv0, cv1 = sv1;

        // issue next-tile staging loads (overlap with this tile's phases)
        const int ntb = tb + TILE;
        if (ntb < hi) {
            const int nn = (ntb + TILE < hi) ? TILE : (hi - ntb);
            if (t * 8 < nn) {
                const int i4 = (ntb + t * 8) >> 2;
                sr0 = __builtin_nontemporal_load(((const i32x4*)rows) + i4);
                sr1 = __builtin_nontemporal_load(((const i32x4*)rows) + i4 + 1);
                sq0 = __builtin_nontemporal_load(((const i32x4*)cols) + i4);
                sq1 = __builtin_nontemporal_load(((const i32x4*)cols) + i4 + 1);
                sv0 = __builtin_nontemporal_load(((const f32x4*)vals) + i4);
                sv1 = __builtin_nontemporal_load(((const f32x4*)vals) + i4 + 1);
            }
        }

        // Phase B: claim slots (8 tracked rtn atomics), build packed records
        unsigned long long r8[8];
        unsigned sl[8];
        if (act) {
#pragma unroll
            for (int k = 0; k < 8; ++k) {
                const int rr = (k < 4) ? cr0[k] : cr1[k - 4];
                const int qq = (k < 4) ? cq0[k] : cq1[k - 4];
                const float vf = (k < 4) ? cv0[k] : cv1[k - 4];
                const unsigned bn = (unsigned)bin_of(rr, qq);
                const unsigned vh = (unsigned)__half_as_ushort(__float2half(vf));
                r8[k] = ((unsigned long long)bn << 55)
                      | ((unsigned long long)(unsigned)(rr & (RB_PX - 1)) << 45)
                      | ((unsigned long long)(unsigned)qq << 26)
                      | (unsigned long long)vh;
                sl[k] = atomicAdd(&cnt[bn], 1u);
            }
        }
        __syncthreads();

        // Phase C: exclusive scan of cnt[512] via per-wave __shfl_up (8 waves),
        // fused cursor advance + counter reset
        unsigned x = 0u, incl = 0u;
        if (t < NBIN) {
            x = cnt[t];
            incl = x;
#pragma unroll
            for (int o = 1; o < 64; o <<= 1) {
                const unsigned y = __shfl_up(incl, (unsigned)o, 64);
                if (lane >= o) incl += y;
            }
            if (lane == 63) wsum[t >> 6] = incl;
        }
        __syncthreads();
        if (t < NBIN) {
            unsigned wo = 0u;
            const int w = t >> 6;
            for (int k = 0; k < w; ++k) wo += wsum[k];
            const unsigned e = wo + incl - x;        // exclusive prefix for bin t
            toff[t] = e;
            ebase[t] = bs2[t] - e;
            bs2[t] += x;
            cnt[t] = 0u;
        }
        __syncthreads();

        // Phase D: place records sorted into LDS
        if (act) {
#pragma unroll
            for (int k = 0; k < 8; ++k) {
                const unsigned bn = (unsigned)(r8[k] >> 55);
                sdata[toff[bn] + sl[k]] = r8[k];
            }
        }
        __syncthreads();

        // Phase E: emission — plain stores (L2 write-combines across tiles);
        // cell-capacity check diverts rare overflow to global list
        for (int j = t; j < n; j += SC2_THREADS) {
            const unsigned long long u = sdata[j];
            const unsigned sb = (unsigned)(u >> 55);
            const unsigned pos = ebase[sb] + (unsigned)j;
            const unsigned cb = ((unsigned)blockIdx.x * NBIN + sb) * CAP;
            const unsigned pk = (unsigned)((u >> 26) & 0x1FFFFFFFu);
            const unsigned short vh = (unsigned short)(u & 0xFFFFu);
            if (pos - cb < CAP) {
                recA[pos] = pk;
                recB[pos] = vh;
            } else {
                const unsigned g = atomicAdd(ovf_n, 1u);
                if (g < OVF_CAP) ovf[g] = u;
            }
        }
        __syncthreads();
    }

    // write per-cell counts (capped) for accum
    if (t < NBIN) {
        const unsigned cb = ((unsigned)blockIdx.x * NBIN + (unsigned)t) * CAP;
        const unsigned total = bs2[t] - cb;
        gcnt[(size_t)blockIdx.x * NBIN + t] = (total < CAP) ? total : CAP;
    }
}

// accumulate one bin from 256 fragments; 3 fixed-point packed u64 no-rtn atomics
// per pixel: 3 u64: #1={q1 : q0+B} #2={q3 : q2+B} #3={q5+NTAG : q4+B}
__global__ __launch_bounds__(ACC_THREADS) void k_accum(
        const unsigned* __restrict__ recA, const unsigned short* __restrict__ recB,
        const unsigned* __restrict__ gcnt, const u32x4* __restrict__ sino_b,
        float* __restrict__ acc) {
    __shared__ unsigned long long l8[RB_PX * 3];   // 24 KB
    __shared__ unsigned fcnt[SCAT_BLOCKS];         //  1 KB
    const int t = threadIdx.x;
    const int bin = blockIdx.x;
    for (int j = t; j < RB_PX * 3; j += ACC_THREADS) l8[j] = 0ull;
    if (t < SCAT_BLOCKS) fcnt[t] = gcnt[(size_t)t * NBIN + bin];
    __syncthreads();

    const int w = t >> 6, lane = t & 63;
    for (int f = w; f < SCAT_BLOCKS; f += 8) {      // wave-strided fragments
        const unsigned n = fcnt[f];
        const unsigned base = ((unsigned)f * NBIN + (unsigned)bin) * CAP;
        for (unsigned j = (unsigned)lane; j < n; j += 64) {
            const unsigned a = recA[base + j];
            const float v = __half2float(__ushort_as_half(recB[base + j]));
            const int col = (int)(a & 0x7FFFFu);
            const int lr  = (int)(a >> 19);
            const u32x4 sv = sino_b[col];
            const int q0 = __float2int_rn(v * __uint_as_float(sv.x << 16)         * FXSCALE);
            const int q1 = __float2int_rn(v * __uint_as_float(sv.x & 0xFFFF0000u) * FXSCALE);
            const int q2 = __float2int_rn(v * __uint_as_float(sv.y << 16)         * FXSCALE);
            const int q3 = __float2int_rn(v * __uint_as_float(sv.y & 0xFFFF0000u) * FXSCALE);
            const int q4 = __float2int_rn(v * __uint_as_float(sv.z << 16)         * FXSCALE);
            const int q5 = __float2int_rn(v * FXSCALE);
            const unsigned b = lds_off(&l8[(unsigned)lr * 3u]);
            ds_add_u64_nr(b,
                ((unsigned long long)(unsigned)q1 << 32) | (unsigned)(q0 + FXB));
            ds_add_u64_nr(b + 8,
                ((unsigned long long)(unsigned)q3 << 32) | (unsigned)(q2 + FXB));
            ds_add_u64_nr(b + 16,
                ((unsigned long long)((unsigned)q5 + NTAG) << 32) | (unsigned)(q4 + FXB));
        }
    }
    lgkm_drain();
    __syncthreads();
    float* dst = acc + (size_t)bin * (RB_PX * 6);
    for (int px = t; px < RB_PX; px += ACC_THREADS) {
        const unsigned long long a0 = l8[px * 3 + 0];
        const unsigned long long a1 = l8[px * 3 + 1];
        const unsigned long long a2 = l8[px * 3 + 2];
        const unsigned hi3 = (unsigned)(a2 >> 32);
        const unsigned n = hi3 >> 24;                     // record count
        const long long nb = (long long)n * FXB;
        float* d = dst + px * 6;
        d[0] = (float)((long long)(unsigned)(a0 & 0xFFFFFFFFull) - nb) * FXINV;
        d[1] = (float)((int)(a0 >> 32)) * FXINV;
        d[2] = (float)((long long)(unsigned)(a1 & 0xFFFFFFFFull) - nb) * FXINV;
        d[3] = (float)((int)(a1 >> 32)) * FXINV;
        d[4] = (float)((long long)(unsigned)(a2 & 0xFFFFFFFFull) - nb) * FXINV;
        d[5] = (float)(hi3 & 0xFFFFFFu) * FXINV;          // sum of vals (positive)
    }
}

// add rare overflow records into acc (runs after k_accum)
__global__ void k_fixup(const unsigned long long* __restrict__ ovf,
                        const unsigned* __restrict__ ovf_n,
                        const u32x4* __restrict__ sino_b,
                        float* __restrict__ acc) {
    unsigned n = *ovf_n;
    if (n > OVF_CAP) n = OVF_CAP;
    for (unsigned i = threadIdx.x; i < n; i += blockDim.x) {
        const unsigned long long u = ovf[i];
        const unsigned sb = (unsigned)(u >> 55);
        const unsigned pk = (unsigned)((u >> 26) & 0x1FFFFFFFu);
        const float v = __half2float(__ushort_as_half((unsigned short)(u & 0xFFFFu)));
        const int col = (int)(pk & 0x7FFFFu);
        const int lr  = (int)(pk >> 19);
        const u32x4 sv = sino_b[col];
        float* d = acc + (size_t)sb * (RB_PX * 6) + (size_t)lr * 6;
        atomicAdd(d + 0, v * __uint_as_float(sv.x << 16));
        atomicAdd(d + 1, v * __uint_as_float(sv.x & 0xFFFF0000u));
        atomicAdd(d + 2, v * __uint_as_float(sv.y << 16));
        atomicAdd(d + 3, v * __uint_as_float(sv.y & 0xFFFF0000u));
        atomicAdd(d + 4, v * __uint_as_float(sv.z << 16));
        atomicAdd(d + 5, v);
    }
}

// sum 4 shards per pixel, divide, write [BSZ][NPIX]
__global__ void k_reduce(const float* __restrict__ acc, float* __restrict__ out) {
    const int p = blockIdx.x * blockDim.x + threadIdx.x;
    if (p < NPIX) {
        const int rbin = p >> RB_SHIFT, lr = p & (RB_PX - 1);
        float n0 = 0.f, n1 = 0.f, n2 = 0.f, n3 = 0.f, n4 = 0.f, den = 0.f;
#pragma unroll
        for (int s = 0; s < NSHARD; ++s) {
            const float* b = acc + ((size_t)(rbin * NSHARD + s) * RB_PX + lr) * 6;
            n0 += b[0]; n1 += b[1]; n2 += b[2];
            n3 += b[3]; n4 += b[4]; den += b[5];
        }
        const float inv = 1.f / den;
        out[0 * (size_t)NPIX + p] = n0 * inv;
        out[1 * (size_t)NPIX + p] = n1 * inv;
        out[2 * (size_t)NPIX + p] = n2 * inv;
        out[3 * (size_t)NPIX + p] = n3 * inv;
        out[4 * (size_t)NPIX + p] = n4 * inv;
    }
}

// ---------------- fallback kernels (small workspace) ----------------

__global__ void bp_scatter_fb_kernel(const float* __restrict__ sino,
                                     const float* __restrict__ vals,
                                     const int*   __restrict__ rows,
                                     const int*   __restrict__ cols,
                                     float* __restrict__ acc) {
    const long long stride = (long long)gridDim.x * blockDim.x;
    for (long long i = (long long)blockIdx.x * blockDim.x + threadIdx.x;
         i < NNZ; i += stride) {
        const float v = vals[i];
        const int   r = rows[i];
        const int   c = cols[i];
        atomicAdd(acc + (size_t)BSZ * NPIX + r, v);
#pragma unroll
        for (int b = 0; b < BSZ; ++b)
            atomicAdd(acc + (size_t)b * NPIX + r, v * sino[(size_t)b * SINO + c]);
    }
}

__global__ void bp_divide_fb_kernel(const float* __restrict__ acc,
                                    float* __restrict__ out) {
    const int i = blockIdx.x * blockDim.x + threadIdx.x;
    if (i < BSZ * NPIX) {
        const int p = i % NPIX;
        out[i] = acc[i] / acc[(size_t)BSZ * NPIX + p];
    }
}

// ---------------- launch ----------------

extern "C" void kernel_launch(void* const* d_in, const int* in_sizes, int n_in,
                              void* d_out, int out_size, void* d_ws, size_t ws_size,
                              hipStream_t stream) {
    const float* sino = (const float*)d_in[0];
    const float* vals = (const float*)d_in[1];
    const int*   rows = (const int*)d_in[2];
    const int*   cols = (const int*)d_in[3];
    float* out = (float*)d_out;

    // workspace layout (bytes, all 16B-aligned):
    //   recA   : 131072 cells * CAP * 4   = 104,857,600
    //   recB   : 131072 cells * CAP * 2   =  52,428,800
    //   sino_b : SINO * 16                =   8,208,000
    //   acc    : NBIN * RB_PX * 6 * 4     =  12,582,912
    //   gcnt   : SCAT_BLOCKS * NBIN * 4   =     524,288
    //   ovf    : OVF_CAP * 8              =     524,288
    //   ovf_n  : 16
    //   total ~ 179.1 MB (< proven >=181.8 MB workspace)
    const size_t recA_b   = (size_t)SCAT_BLOCKS * NBIN * CAP * 4;
    const size_t recB_b   = (size_t)SCAT_BLOCKS * NBIN * CAP * 2;
    const size_t sino_b_b = (size_t)SINO * 16;
    const size_t acc_b    = (size_t)NBIN * RB_PX * 6 * 4;
    const size_t gcnt_b   = (size_t)SCAT_BLOCKS * NBIN * 4;
    const size_t ovf_b    = (size_t)OVF_CAP * 8;
    const size_t need = recA_b + recB_b + sino_b_b + acc_b + gcnt_b + ovf_b + 16;

    if (ws_size >= need) {
        char* w = (char*)d_ws;
        unsigned*       recA = (unsigned*)w;                w += recA_b;
        unsigned short* recB = (unsigned short*)w;          w += recB_b;
        u32x4*    sinob  = (u32x4*)w;                       w += sino_b_b;
        float*    acc    = (float*)w;                       w += acc_b;
        unsigned* gcnt   = (unsigned*)w;                    w += gcnt_b;
        unsigned long long* ovf = (unsigned long long*)w;   w += ovf_b;
        unsigned* ovf_n  = (unsigned*)w;

        (void)hipMemsetAsync(ovf_n, 0, 4, stream);
        k_sino_bf16<<<(SINO + 255) / 256, 256, 0, stream>>>(sino, sinob);
        k_scatter<<<SCAT_BLOCKS, SC2_THREADS, 0, stream>>>(
            vals, rows, cols, recA, recB, gcnt, ovf, ovf_n);
        k_accum<<<NBIN, ACC_THREADS, 0, stream>>>(recA, recB, gcnt, sinob, acc);
        k_fixup<<<1, 256, 0, stream>>>(ovf, ovf_n, sinob, acc);
        k_reduce<<<(NPIX + 255) / 256, 256, 0, stream>>>(acc, out);
    } else {
        float* acc = (float*)d_ws;
        (void)hipMemsetAsync(acc, 0, (size_t)(BSZ + 1) * NPIX * sizeof(float), stream);
        bp_scatter_fb_kernel<<<2048, 256, 0, stream>>>(sino, vals, rows, cols, acc);
        bp_divide_fb_kernel<<<(BSZ * NPIX + 255) / 256, 256, 0, stream>>>(acc, out);
    }
}

// Round 15
// 249.918 us; speedup vs baseline: 1.6700x; 1.0014x over previous
//
#include <hip/hip_runtime.h>
#include <hip/hip_fp16.h>

#define BSZ  5
#define PROJ 1000
#define DET  513
#define IMG  362
#define NPIX (IMG * IMG)          // 131044
#define SINO (PROJ * DET)         // 513000
#define NNZ  20000000

#define NSHARD     4
#define SHARD_COLS (SINO / NSHARD)   // 128250
#define RB_SHIFT   10
#define RB_PX      1024
#define NRBIN      128
#define NBIN       (NRBIN * NSHARD)  // 512

#define SCAT_BLOCKS  256
#define CHUNK        78128           // ceil(NNZ/256) rounded to mult of 16
#define TILE         4096
#define SC2_THREADS  512

#define CAP        200               // slots per (bin,block) cell
#define CELLS_PER_BIN (SCAT_BLOCKS * CAP)   // 51200 slots per bin
#define OVF_CAP    65536

#define ACC_THREADS  512

// fixed-point: scale 2^14, bias 2^18, n-tag 2^24 in slot-3 high
#define FXSCALE 16384.0f
#define FXINV   (1.0f / 16384.0f)
#define FXB     262144               // 2^18
#define NTAG    0x1000000u           // 2^24

typedef int      i32x4 __attribute__((ext_vector_type(4)));
typedef float    f32x4 __attribute__((ext_vector_type(4)));
typedef unsigned u32x4 __attribute__((ext_vector_type(4)));

// no-return LDS atomics (fire-and-forget).
__device__ __forceinline__ unsigned lds_off(const void* p) {
    return (unsigned)(size_t)p;
}
__device__ __forceinline__ void ds_add_u64_nr(unsigned off, unsigned long long v) {
    asm volatile("ds_add_u64 %0, %1" :: "v"(off), "v"(v) : "memory");
}
// per-wave drain: inline-asm DS ops COMPLETE before the following barrier.
__device__ __forceinline__ void lgkm_drain() {
    asm volatile("s_waitcnt lgkmcnt(0)" ::: "memory");
}

__device__ __forceinline__ int bin_of(int row, int col) {
    return ((row >> RB_SHIFT) << 2) | (col / SHARD_COLS);
}

// ---------------- fast path kernels ----------------

// single pass: sino bf16 prologue + tile-local counting sort into [bin][blk] cells
// LDS record: [63:55]=bin(9) [54:45]=lr(10) [44:26]=col(19) [15:0]=fp16 val
__global__ __launch_bounds__(SC2_THREADS) void k_scatter(
        const float* __restrict__ sino, u32x4* __restrict__ sino_b,
        const float* __restrict__ vals, const int* __restrict__ rows,
        const int* __restrict__ cols,
        unsigned* __restrict__ recA, unsigned short* __restrict__ recB,
        unsigned* __restrict__ gcnt,
        unsigned long long* __restrict__ ovf, unsigned* __restrict__ ovf_n) {
    __shared__ unsigned cnt[NBIN];
    __shared__ unsigned toff[NBIN];
    __shared__ unsigned ebase[NBIN];
    __shared__ unsigned bs2[NBIN];
    __shared__ unsigned wsum[8];
    __shared__ unsigned long long sdata[TILE];   // 32 KB
    const int t = threadIdx.x;
    const int lane = t & 63;

    // ---- sino -> bf16 packed table prologue (4 cols/thread); only accum reads it
    {
        const int cbase = blockIdx.x * (SC2_THREADS * 4) + t * 4;
#pragma unroll
        for (int k = 0; k < 4; ++k) {
            const int c = cbase + k;
            if (c < SINO) {
                unsigned b[5];
#pragma unroll
                for (int j = 0; j < 5; ++j) {
                    const unsigned u = __float_as_uint(sino[(size_t)j * SINO + c]);
                    b[j] = (u + 0x7FFFu + ((u >> 16) & 1u)) >> 16;   // RNE to bf16
                }
                u32x4 o;
                o.x = b[0] | (b[1] << 16);
                o.y = b[2] | (b[3] << 16);
                o.z = b[4];
                o.w = 0u;
                sino_b[c] = o;
            }
        }
    }

    const int lo = blockIdx.x * CHUNK;
    const int hi = (lo + CHUNK < NNZ) ? lo + CHUNK : NNZ;
    if (lo >= hi) return;

    if (t < NBIN) {
        // transposed cell base: cell (bin, blk) at (bin*SCAT_BLOCKS + blk)*CAP
        bs2[t] = ((unsigned)t * SCAT_BLOCKS + (unsigned)blockIdx.x) * CAP;
        cnt[t] = 0u;
    }

    // stage tile 0 (8 records/thread)
    i32x4 sr0, sr1, sq0, sq1; f32x4 sv0, sv1;
    {
        const int n0 = (lo + TILE < hi) ? TILE : (hi - lo);
        if (t * 8 < n0) {
            const int i4 = (lo + t * 8) >> 2;
            sr0 = __builtin_nontemporal_load(((const i32x4*)rows) + i4);
            sr1 = __builtin_nontemporal_load(((const i32x4*)rows) + i4 + 1);
            sq0 = __builtin_nontemporal_load(((const i32x4*)cols) + i4);
            sq1 = __builtin_nontemporal_load(((const i32x4*)cols) + i4 + 1);
            sv0 = __builtin_nontemporal_load(((const f32x4*)vals) + i4);
            sv1 = __builtin_nontemporal_load(((const f32x4*)vals) + i4 + 1);
        }
    }
    __syncthreads();

    for (int tb = lo; tb < hi; tb += TILE) {
        const int n = (tb + TILE < hi) ? TILE : (hi - tb);   // mult of 16
        const bool act = (t * 8) < n;

        const i32x4 cr0 = sr0, cr1 = sr1, cq0 = sq0, cq1 = sq1;
        const f32x4 cv0 = sv0, cv1 = sv1;

        // issue next-tile staging loads (overlap with this tile's phases)
        const int ntb = tb + TILE;
        if (ntb < hi) {
            const int nn = (ntb + TILE < hi) ? TILE : (hi - ntb);
            if (t * 8 < nn) {
                const int i4 = (ntb + t * 8) >> 2;
                sr0 = __builtin_nontemporal_load(((const i32x4*)rows) + i4);
                sr1 = __builtin_nontemporal_load(((const i32x4*)rows) + i4 + 1);
                sq0 = __builtin_nontemporal_load(((const i32x4*)cols) + i4);
                sq1 = __builtin_nontemporal_load(((const i32x4*)cols) + i4 + 1);
                sv0 = __builtin_nontemporal_load(((const f32x4*)vals) + i4);
                sv1 = __builtin_nontemporal_load(((const f32x4*)vals) + i4 + 1);
            }
        }

        // Phase B: claim slots (8 tracked rtn atomics), build packed records
        unsigned long long r8[8];
        unsigned sl[8];
        if (act) {
#pragma unroll
            for (int k = 0; k < 8; ++k) {
                const int rr = (k < 4) ? cr0[k] : cr1[k - 4];
                const int qq = (k < 4) ? cq0[k] : cq1[k - 4];
                const float vf = (k < 4) ? cv0[k] : cv1[k - 4];
                const unsigned bn = (unsigned)bin_of(rr, qq);
                const unsigned vh = (unsigned)__half_as_ushort(__float2half(vf));
                r8[k] = ((unsigned long long)bn << 55)
                      | ((unsigned long long)(unsigned)(rr & (RB_PX - 1)) << 45)
                      | ((unsigned long long)(unsigned)qq << 26)
                      | (unsigned long long)vh;
                sl[k] = atomicAdd(&cnt[bn], 1u);
            }
        }
        __syncthreads();

        // Phase C: exclusive scan of cnt[512] via per-wave __shfl_up (8 waves),
        // fused cursor advance + counter reset
        unsigned x = 0u, incl = 0u;
        if (t < NBIN) {
            x = cnt[t];
            incl = x;
#pragma unroll
            for (int o = 1; o < 64; o <<= 1) {
                const unsigned y = __shfl_up(incl, (unsigned)o, 64);
                if (lane >= o) incl += y;
            }
            if (lane == 63) wsum[t >> 6] = incl;
        }
        __syncthreads();
        if (t < NBIN) {
            unsigned wo = 0u;
            const int w = t >> 6;
            for (int k = 0; k < w; ++k) wo += wsum[k];
            const unsigned e = wo + incl - x;        // exclusive prefix for bin t
            toff[t] = e;
            ebase[t] = bs2[t] - e;
            bs2[t] += x;
            cnt[t] = 0u;
        }
        __syncthreads();

        // Phase D: place records sorted into LDS
        if (act) {
#pragma unroll
            for (int k = 0; k < 8; ++k) {
                const unsigned bn = (unsigned)(r8[k] >> 55);
                sdata[toff[bn] + sl[k]] = r8[k];
            }
        }
        __syncthreads();

        // Phase E: emission — plain stores; cell-capacity check -> overflow list
        for (int j = t; j < n; j += SC2_THREADS) {
            const unsigned long long u = sdata[j];
            const unsigned sb = (unsigned)(u >> 55);
            const unsigned pos = ebase[sb] + (unsigned)j;
            const unsigned cb = (sb * SCAT_BLOCKS + (unsigned)blockIdx.x) * CAP;
            const unsigned pk = (unsigned)((u >> 26) & 0x1FFFFFFFu);
            const unsigned short vh = (unsigned short)(u & 0xFFFFu);
            if (pos - cb < CAP) {
                recA[pos] = pk;
                recB[pos] = vh;
            } else {
                const unsigned g = atomicAdd(ovf_n, 1u);
                if (g < OVF_CAP) ovf[g] = u;
            }
        }
        __syncthreads();
    }

    // write per-cell counts (capped) for accum: gcnt[blk][bin]
    if (t < NBIN) {
        const unsigned cb = ((unsigned)t * SCAT_BLOCKS + (unsigned)blockIdx.x) * CAP;
        const unsigned total = bs2[t] - cb;
        gcnt[(size_t)blockIdx.x * NBIN + t] = (total < CAP) ? total : CAP;
    }
}

// accumulate one bin from its contiguous [bin][blk] cell region (flat masked scan)
// per pixel: 3 u64: #1={q1 : q0+B} #2={q3 : q2+B} #3={q5+NTAG : q4+B}
__global__ __launch_bounds__(ACC_THREADS) void k_accum(
        const unsigned* __restrict__ recA, const unsigned short* __restrict__ recB,
        const unsigned* __restrict__ gcnt, const u32x4* __restrict__ sino_b,
        const unsigned long long* __restrict__ ovf, const unsigned* __restrict__ ovf_n,
        float* __restrict__ acc) {
    __shared__ unsigned long long l8[RB_PX * 3];   // 24 KB
    __shared__ unsigned fcnt[SCAT_BLOCKS];         //  1 KB
    const int t = threadIdx.x;
    const int bin = blockIdx.x;
    for (int j = t; j < RB_PX * 3; j += ACC_THREADS) l8[j] = 0ull;
    if (t < SCAT_BLOCKS) fcnt[t] = gcnt[(size_t)t * NBIN + bin];
    __syncthreads();

    const unsigned binbase = (unsigned)bin * CELLS_PER_BIN;
    for (unsigned i = (unsigned)t; i < CELLS_PER_BIN; i += ACC_THREADS) {
        const unsigned frag = i / CAP;             // magic-mul divide by 200
        const unsigned slot = i - frag * CAP;
        const unsigned a = recA[binbase + i];      // coalesced sequential
        const unsigned short hraw = recB[binbase + i];
        if (slot < fcnt[frag]) {
            const float v = __half2float(__ushort_as_half(hraw));
            const int col = (int)(a & 0x7FFFFu);
            const int lr  = (int)(a >> 19);
            const u32x4 sv = sino_b[col];
            const int q0 = __float2int_rn(v * __uint_as_float(sv.x << 16)         * FXSCALE);
            const int q1 = __float2int_rn(v * __uint_as_float(sv.x & 0xFFFF0000u) * FXSCALE);
            const int q2 = __float2int_rn(v * __uint_as_float(sv.y << 16)         * FXSCALE);
            const int q3 = __float2int_rn(v * __uint_as_float(sv.y & 0xFFFF0000u) * FXSCALE);
            const int q4 = __float2int_rn(v * __uint_as_float(sv.z << 16)         * FXSCALE);
            const int q5 = __float2int_rn(v * FXSCALE);
            const unsigned b = lds_off(&l8[(unsigned)lr * 3u]);
            ds_add_u64_nr(b,
                ((unsigned long long)(unsigned)q1 << 32) | (unsigned)(q0 + FXB));
            ds_add_u64_nr(b + 8,
                ((unsigned long long)(unsigned)q3 << 32) | (unsigned)(q2 + FXB));
            ds_add_u64_nr(b + 16,
                ((unsigned long long)((unsigned)q5 + NTAG) << 32) | (unsigned)(q4 + FXB));
        }
    }

    // fold in rare overflow records for this bin (same fixed-point path)
    {
        unsigned n = *ovf_n;
        if (n > OVF_CAP) n = OVF_CAP;
        for (unsigned i = (unsigned)t; i < n; i += ACC_THREADS) {
            const unsigned long long u = ovf[i];
            if ((unsigned)(u >> 55) != (unsigned)bin) continue;
            const float v = __half2float(__ushort_as_half((unsigned short)(u & 0xFFFFu)));
            const unsigned pk = (unsigned)((u >> 26) & 0x1FFFFFFFu);
            const int col = (int)(pk & 0x7FFFFu);
            const int lr  = (int)(pk >> 19);
            const u32x4 sv = sino_b[col];
            const int q0 = __float2int_rn(v * __uint_as_float(sv.x << 16)         * FXSCALE);
            const int q1 = __float2int_rn(v * __uint_as_float(sv.x & 0xFFFF0000u) * FXSCALE);
            const int q2 = __float2int_rn(v * __uint_as_float(sv.y << 16)         * FXSCALE);
            const int q3 = __float2int_rn(v * __uint_as_float(sv.y & 0xFFFF0000u) * FXSCALE);
            const int q4 = __float2int_rn(v * __uint_as_float(sv.z << 16)         * FXSCALE);
            const int q5 = __float2int_rn(v * FXSCALE);
            const unsigned b = lds_off(&l8[(unsigned)lr * 3u]);
            ds_add_u64_nr(b,
                ((unsigned long long)(unsigned)q1 << 32) | (unsigned)(q0 + FXB));
            ds_add_u64_nr(b + 8,
                ((unsigned long long)(unsigned)q3 << 32) | (unsigned)(q2 + FXB));
            ds_add_u64_nr(b + 16,
                ((unsigned long long)((unsigned)q5 + NTAG) << 32) | (unsigned)(q4 + FXB));
        }
    }
    lgkm_drain();
    __syncthreads();

    float* dst = acc + (size_t)bin * (RB_PX * 6);
    for (int px = t; px < RB_PX; px += ACC_THREADS) {
        const unsigned long long a0 = l8[px * 3 + 0];
        const unsigned long long a1 = l8[px * 3 + 1];
        const unsigned long long a2 = l8[px * 3 + 2];
        const unsigned hi3 = (unsigned)(a2 >> 32);
        const unsigned n = hi3 >> 24;                     // record count
        const long long nb = (long long)n * FXB;
        float* d = dst + px * 6;
        d[0] = (float)((long long)(unsigned)(a0 & 0xFFFFFFFFull) - nb) * FXINV;
        d[1] = (float)((int)(a0 >> 32)) * FXINV;
        d[2] = (float)((long long)(unsigned)(a1 & 0xFFFFFFFFull) - nb) * FXINV;
        d[3] = (float)((int)(a1 >> 32)) * FXINV;
        d[4] = (float)((long long)(unsigned)(a2 & 0xFFFFFFFFull) - nb) * FXINV;
        d[5] = (float)(hi3 & 0xFFFFFFu) * FXINV;          // sum of vals (positive)
    }
}

// sum 4 shards per pixel, divide, write [BSZ][NPIX]
__global__ void k_reduce(const float* __restrict__ acc, float* __restrict__ out) {
    const int p = blockIdx.x * blockDim.x + threadIdx.x;
    if (p < NPIX) {
        const int rbin = p >> RB_SHIFT, lr = p & (RB_PX - 1);
        float n0 = 0.f, n1 = 0.f, n2 = 0.f, n3 = 0.f, n4 = 0.f, den = 0.f;
#pragma unroll
        for (int s = 0; s < NSHARD; ++s) {
            const float* b = acc + ((size_t)(rbin * NSHARD + s) * RB_PX + lr) * 6;
            n0 += b[0]; n1 += b[1]; n2 += b[2];
            n3 += b[3]; n4 += b[4]; den += b[5];
        }
        const float inv = 1.f / den;
        out[0 * (size_t)NPIX + p] = n0 * inv;
        out[1 * (size_t)NPIX + p] = n1 * inv;
        out[2 * (size_t)NPIX + p] = n2 * inv;
        out[3 * (size_t)NPIX + p] = n3 * inv;
        out[4 * (size_t)NPIX + p] = n4 * inv;
    }
}

// ---------------- fallback kernels (small workspace) ----------------

__global__ void bp_scatter_fb_kernel(const float* __restrict__ sino,
                                     const float* __restrict__ vals,
                                     const int*   __restrict__ rows,
                                     const int*   __restrict__ cols,
                                     float* __restrict__ acc) {
    const long long stride = (long long)gridDim.x * blockDim.x;
    for (long long i = (long long)blockIdx.x * blockDim.x + threadIdx.x;
         i < NNZ; i += stride) {
        const float v = vals[i];
        const int   r = rows[i];
        const int   c = cols[i];
        atomicAdd(acc + (size_t)BSZ * NPIX + r, v);
#pragma unroll
        for (int b = 0; b < BSZ; ++b)
            atomicAdd(acc + (size_t)b * NPIX + r, v * sino[(size_t)b * SINO + c]);
    }
}

__global__ void bp_divide_fb_kernel(const float* __restrict__ acc,
                                    float* __restrict__ out) {
    const int i = blockIdx.x * blockDim.x + threadIdx.x;
    if (i < BSZ * NPIX) {
        const int p = i % NPIX;
        out[i] = acc[i] / acc[(size_t)BSZ * NPIX + p];
    }
}

// ---------------- launch ----------------

extern "C" void kernel_launch(void* const* d_in, const int* in_sizes, int n_in,
                              void* d_out, int out_size, void* d_ws, size_t ws_size,
                              hipStream_t stream) {
    const float* sino = (const float*)d_in[0];
    const float* vals = (const float*)d_in[1];
    const int*   rows = (const int*)d_in[2];
    const int*   cols = (const int*)d_in[3];
    float* out = (float*)d_out;

    // workspace layout (bytes, all 16B-aligned):
    //   recA   : 512 bins * 51200 * 4     = 104,857,600
    //   recB   : 512 bins * 51200 * 2     =  52,428,800
    //   sino_b : SINO * 16                =   8,208,000
    //   acc    : NBIN * RB_PX * 6 * 4     =  12,582,912
    //   gcnt   : SCAT_BLOCKS * NBIN * 4   =     524,288
    //   ovf    : OVF_CAP * 8              =     524,288
    //   ovf_n  : 16
    //   total ~ 179.1 MB
    const size_t recA_b   = (size_t)NBIN * CELLS_PER_BIN * 4;
    const size_t recB_b   = (size_t)NBIN * CELLS_PER_BIN * 2;
    const size_t sino_b_b = (size_t)SINO * 16;
    const size_t acc_b    = (size_t)NBIN * RB_PX * 6 * 4;
    const size_t gcnt_b   = (size_t)SCAT_BLOCKS * NBIN * 4;
    const size_t ovf_b    = (size_t)OVF_CAP * 8;
    const size_t need = recA_b + recB_b + sino_b_b + acc_b + gcnt_b + ovf_b + 16;

    if (ws_size >= need) {
        char* w = (char*)d_ws;
        unsigned*       recA = (unsigned*)w;                w += recA_b;
        unsigned short* recB = (unsigned short*)w;          w += recB_b;
        u32x4*    sinob  = (u32x4*)w;                       w += sino_b_b;
        float*    acc    = (float*)w;                       w += acc_b;
        unsigned* gcnt   = (unsigned*)w;                    w += gcnt_b;
        unsigned long long* ovf = (unsigned long long*)w;   w += ovf_b;
        unsigned* ovf_n  = (unsigned*)w;

        (void)hipMemsetAsync(ovf_n, 0, 4, stream);
        k_scatter<<<SCAT_BLOCKS, SC2_THREADS, 0, stream>>>(
            sino, sinob, vals, rows, cols, recA, recB, gcnt, ovf, ovf_n);
        k_accum<<<NBIN, ACC_THREADS, 0, stream>>>(
            recA, recB, gcnt, sinob, ovf, ovf_n, acc);
        k_reduce<<<(NPIX + 255) / 256, 256, 0, stream>>>(acc, out);
    } else {
        float* acc = (float*)d_ws;
        (void)hipMemsetAsync(acc, 0, (size_t)(BSZ + 1) * NPIX * sizeof(float), stream);
        bp_scatter_fb_kernel<<<2048, 256, 0, stream>>>(sino, vals, rows, cols, acc);
        bp_divide_fb_kernel<<<(BSZ * NPIX + 255) / 256, 256, 0, stream>>>(acc, out);
    }
}

// Round 16
// 225.183 us; speedup vs baseline: 1.8535x; 1.1098x over previous
//
#include <hip/hip_runtime.h>
#include <hip/hip_fp16.h>

#define BSZ  5
#define PROJ 1000
#define DET  513
#define IMG  362
#define NPIX (IMG * IMG)          // 131044
#define SINO (PROJ * DET)         // 513000
#define NNZ  20000000

#define NSHARD     4
#define SHARD_COLS (SINO / NSHARD)   // 128250
#define RB_SHIFT   10
#define RB_PX      1024
#define NRBIN      128
#define NBIN       (NRBIN * NSHARD)  // 512

#define SCAT_BLOCKS  256
#define CHUNK        78128           // ceil(NNZ/256) rounded to mult of 16
#define TILE         8192
#define SCT_THREADS  1024

#define CAP        200               // slots per (bin,block) cell
#define CELLS_PER_BIN (SCAT_BLOCKS * CAP)   // 51200 slots per bin
#define OVF_CAP    65536

#define ACC_THREADS  512

// fixed-point: scale 2^14, bias 2^18, n-tag 2^24 in slot-3 high
#define FXSCALE 16384.0f
#define FXINV   (1.0f / 16384.0f)
#define FXB     262144               // 2^18
#define NTAG    0x1000000u           // 2^24

typedef int      i32x4 __attribute__((ext_vector_type(4)));
typedef float    f32x4 __attribute__((ext_vector_type(4)));
typedef unsigned u32x4 __attribute__((ext_vector_type(4)));

// no-return LDS atomics (fire-and-forget).
__device__ __forceinline__ unsigned lds_off(const void* p) {
    return (unsigned)(size_t)p;
}
__device__ __forceinline__ void ds_add_u64_nr(unsigned off, unsigned long long v) {
    asm volatile("ds_add_u64 %0, %1" :: "v"(off), "v"(v) : "memory");
}
// per-wave drain: inline-asm DS ops COMPLETE before the following barrier.
__device__ __forceinline__ void lgkm_drain() {
    asm volatile("s_waitcnt lgkmcnt(0)" ::: "memory");
}

__device__ __forceinline__ int bin_of(int row, int col) {
    return ((row >> RB_SHIFT) << 2) | (col / SHARD_COLS);
}

// ---------------- fast path kernels ----------------

// single pass: sino bf16 prologue + tile-local counting sort into [bin][blk] cells
// LDS record: [63:55]=bin(9) [54:45]=lr(10) [44:26]=col(19) [15:0]=fp16 val
__global__ __launch_bounds__(SCT_THREADS) void k_scatter(
        const float* __restrict__ sino, u32x4* __restrict__ sino_b,
        const float* __restrict__ vals, const int* __restrict__ rows,
        const int* __restrict__ cols,
        unsigned* __restrict__ recA, unsigned short* __restrict__ recB,
        unsigned* __restrict__ gcnt,
        unsigned long long* __restrict__ ovf, unsigned* __restrict__ ovf_n) {
    __shared__ unsigned cnt[NBIN];
    __shared__ unsigned toff[NBIN];
    __shared__ unsigned ebase[NBIN];
    __shared__ unsigned bs2[NBIN];
    __shared__ unsigned wsum[8];
    __shared__ unsigned long long sdata[TILE];   // 64 KB
    const int t = threadIdx.x;
    const int lane = t & 63;

    // ---- sino -> bf16 packed table prologue (2 cols/thread); only accum reads it
    {
        const int cbase = blockIdx.x * (SCT_THREADS * 2) + t * 2;
#pragma unroll
        for (int k = 0; k < 2; ++k) {
            const int c = cbase + k;
            if (c < SINO) {
                unsigned b[5];
#pragma unroll
                for (int j = 0; j < 5; ++j) {
                    const unsigned u = __float_as_uint(sino[(size_t)j * SINO + c]);
                    b[j] = (u + 0x7FFFu + ((u >> 16) & 1u)) >> 16;   // RNE to bf16
                }
                u32x4 o;
                o.x = b[0] | (b[1] << 16);
                o.y = b[2] | (b[3] << 16);
                o.z = b[4];
                o.w = 0u;
                sino_b[c] = o;
            }
        }
    }

    const int lo = blockIdx.x * CHUNK;
    const int hi = (lo + CHUNK < NNZ) ? lo + CHUNK : NNZ;
    if (lo >= hi) return;

    if (t < NBIN) {
        // transposed cell base: cell (bin, blk) at (bin*SCAT_BLOCKS + blk)*CAP
        bs2[t] = ((unsigned)t * SCAT_BLOCKS + (unsigned)blockIdx.x) * CAP;
        cnt[t] = 0u;
    }

    // stage tile 0 (8 records/thread)
    i32x4 sr0, sr1, sq0, sq1; f32x4 sv0, sv1;
    {
        const int n0 = (lo + TILE < hi) ? TILE : (hi - lo);
        if (t * 8 < n0) {
            const int i4 = (lo + t * 8) >> 2;
            sr0 = __builtin_nontemporal_load(((const i32x4*)rows) + i4);
            sr1 = __builtin_nontemporal_load(((const i32x4*)rows) + i4 + 1);
            sq0 = __builtin_nontemporal_load(((const i32x4*)cols) + i4);
            sq1 = __builtin_nontemporal_load(((const i32x4*)cols) + i4 + 1);
            sv0 = __builtin_nontemporal_load(((const f32x4*)vals) + i4);
            sv1 = __builtin_nontemporal_load(((const f32x4*)vals) + i4 + 1);
        }
    }
    __syncthreads();

    for (int tb = lo; tb < hi; tb += TILE) {
        const int n = (tb + TILE < hi) ? TILE : (hi - tb);   // mult of 16
        const bool act = (t * 8) < n;

        const i32x4 cr0 = sr0, cr1 = sr1, cq0 = sq0, cq1 = sq1;
        const f32x4 cv0 = sv0, cv1 = sv1;

        // issue next-tile staging loads (overlap with this tile's phases)
        const int ntb = tb + TILE;
        if (ntb < hi) {
            const int nn = (ntb + TILE < hi) ? TILE : (hi - ntb);
            if (t * 8 < nn) {
                const int i4 = (ntb + t * 8) >> 2;
                sr0 = __builtin_nontemporal_load(((const i32x4*)rows) + i4);
                sr1 = __builtin_nontemporal_load(((const i32x4*)rows) + i4 + 1);
                sq0 = __builtin_nontemporal_load(((const i32x4*)cols) + i4);
                sq1 = __builtin_nontemporal_load(((const i32x4*)cols) + i4 + 1);
                sv0 = __builtin_nontemporal_load(((const f32x4*)vals) + i4);
                sv1 = __builtin_nontemporal_load(((const f32x4*)vals) + i4 + 1);
            }
        }

        // Phase B: claim slots (8 tracked rtn atomics), build packed records
        unsigned long long r8[8];
        unsigned sl[8];
        if (act) {
#pragma unroll
            for (int k = 0; k < 8; ++k) {
                const int rr = (k < 4) ? cr0[k] : cr1[k - 4];
                const int qq = (k < 4) ? cq0[k] : cq1[k - 4];
                const float vf = (k < 4) ? cv0[k] : cv1[k - 4];
                const unsigned bn = (unsigned)bin_of(rr, qq);
                const unsigned vh = (unsigned)__half_as_ushort(__float2half(vf));
                r8[k] = ((unsigned long long)bn << 55)
                      | ((unsigned long long)(unsigned)(rr & (RB_PX - 1)) << 45)
                      | ((unsigned long long)(unsigned)qq << 26)
                      | (unsigned long long)vh;
                sl[k] = atomicAdd(&cnt[bn], 1u);
            }
        }
        __syncthreads();

        // Phase C: exclusive scan of cnt[512] via per-wave __shfl_up (8 waves),
        // fused cursor advance + counter reset
        unsigned x = 0u, incl = 0u;
        if (t < NBIN) {
            x = cnt[t];
            incl = x;
#pragma unroll
            for (int o = 1; o < 64; o <<= 1) {
                const unsigned y = __shfl_up(incl, (unsigned)o, 64);
                if (lane >= o) incl += y;
            }
            if (lane == 63) wsum[t >> 6] = incl;
        }
        __syncthreads();
        if (t < NBIN) {
            unsigned wo = 0u;
            const int w = t >> 6;
            for (int k = 0; k < w; ++k) wo += wsum[k];
            const unsigned e = wo + incl - x;        // exclusive prefix for bin t
            toff[t] = e;
            ebase[t] = bs2[t] - e;
            bs2[t] += x;
            cnt[t] = 0u;
        }
        __syncthreads();

        // Phase D: place records sorted into LDS
        if (act) {
#pragma unroll
            for (int k = 0; k < 8; ++k) {
                const unsigned bn = (unsigned)(r8[k] >> 55);
                sdata[toff[bn] + sl[k]] = r8[k];
            }
        }
        __syncthreads();

        // Phase E: emission — plain stores; cell-capacity check -> overflow list
        for (int j = t; j < n; j += SCT_THREADS) {
            const unsigned long long u = sdata[j];
            const unsigned sb = (unsigned)(u >> 55);
            const unsigned pos = ebase[sb] + (unsigned)j;
            const unsigned cb = (sb * SCAT_BLOCKS + (unsigned)blockIdx.x) * CAP;
            const unsigned pk = (unsigned)((u >> 26) & 0x1FFFFFFFu);
            const unsigned short vh = (unsigned short)(u & 0xFFFFu);
            if (pos - cb < CAP) {
                recA[pos] = pk;
                recB[pos] = vh;
            } else {
                const unsigned g = atomicAdd(ovf_n, 1u);
                if (g < OVF_CAP) ovf[g] = u;
            }
        }
        __syncthreads();
    }

    // write per-cell counts (capped) for accum: gcnt[blk][bin]
    if (t < NBIN) {
        const unsigned cb = ((unsigned)t * SCAT_BLOCKS + (unsigned)blockIdx.x) * CAP;
        const unsigned total = bs2[t] - cb;
        gcnt[(size_t)blockIdx.x * NBIN + t] = (total < CAP) ? total : CAP;
    }
}

// accumulate one bin from its contiguous [bin][blk] cell region (flat masked scan)
// per pixel: 3 u64: #1={q1 : q0+B} #2={q3 : q2+B} #3={q5+NTAG : q4+B}
__global__ __launch_bounds__(ACC_THREADS) void k_accum(
        const unsigned* __restrict__ recA, const unsigned short* __restrict__ recB,
        const unsigned* __restrict__ gcnt, const u32x4* __restrict__ sino_b,
        const unsigned long long* __restrict__ ovf, const unsigned* __restrict__ ovf_n,
        float* __restrict__ acc) {
    __shared__ unsigned long long l8[RB_PX * 3];   // 24 KB
    __shared__ unsigned fcnt[SCAT_BLOCKS];         //  1 KB
    const int t = threadIdx.x;
    const int bin = blockIdx.x;
    for (int j = t; j < RB_PX * 3; j += ACC_THREADS) l8[j] = 0ull;
    if (t < SCAT_BLOCKS) fcnt[t] = gcnt[(size_t)t * NBIN + bin];
    __syncthreads();

    const unsigned binbase = (unsigned)bin * CELLS_PER_BIN;
    for (unsigned i = (unsigned)t; i < CELLS_PER_BIN; i += ACC_THREADS) {
        const unsigned frag = i / CAP;             // magic-mul divide by 200
        const unsigned slot = i - frag * CAP;
        const unsigned a = recA[binbase + i];      // coalesced sequential
        const unsigned short hraw = recB[binbase + i];
        if (slot < fcnt[frag]) {
            const float v = __half2float(__ushort_as_half(hraw));
            const int col = (int)(a & 0x7FFFFu);
            const int lr  = (int)(a >> 19);
            const u32x4 sv = sino_b[col];
            const int q0 = __float2int_rn(v * __uint_as_float(sv.x << 16)         * FXSCALE);
            const int q1 = __float2int_rn(v * __uint_as_float(sv.x & 0xFFFF0000u) * FXSCALE);
            const int q2 = __float2int_rn(v * __uint_as_float(sv.y << 16)         * FXSCALE);
            const int q3 = __float2int_rn(v * __uint_as_float(sv.y & 0xFFFF0000u) * FXSCALE);
            const int q4 = __float2int_rn(v * __uint_as_float(sv.z << 16)         * FXSCALE);
            const int q5 = __float2int_rn(v * FXSCALE);
            const unsigned b = lds_off(&l8[(unsigned)lr * 3u]);
            ds_add_u64_nr(b,
                ((unsigned long long)(unsigned)q1 << 32) | (unsigned)(q0 + FXB));
            ds_add_u64_nr(b + 8,
                ((unsigned long long)(unsigned)q3 << 32) | (unsigned)(q2 + FXB));
            ds_add_u64_nr(b + 16,
                ((unsigned long long)((unsigned)q5 + NTAG) << 32) | (unsigned)(q4 + FXB));
        }
    }

    // fold in rare overflow records for this bin (same fixed-point path)
    {
        unsigned n = *ovf_n;
        if (n > OVF_CAP) n = OVF_CAP;
        for (unsigned i = (unsigned)t; i < n; i += ACC_THREADS) {
            const unsigned long long u = ovf[i];
            if ((unsigned)(u >> 55) != (unsigned)bin) continue;
            const float v = __half2float(__ushort_as_half((unsigned short)(u & 0xFFFFu)));
            const unsigned pk = (unsigned)((u >> 26) & 0x1FFFFFFFu);
            const int col = (int)(pk & 0x7FFFFu);
            const int lr  = (int)(pk >> 19);
            const u32x4 sv = sino_b[col];
            const int q0 = __float2int_rn(v * __uint_as_float(sv.x << 16)         * FXSCALE);
            const int q1 = __float2int_rn(v * __uint_as_float(sv.x & 0xFFFF0000u) * FXSCALE);
            const int q2 = __float2int_rn(v * __uint_as_float(sv.y << 16)         * FXSCALE);
            const int q3 = __float2int_rn(v * __uint_as_float(sv.y & 0xFFFF0000u) * FXSCALE);
            const int q4 = __float2int_rn(v * __uint_as_float(sv.z << 16)         * FXSCALE);
            const int q5 = __float2int_rn(v * FXSCALE);
            const unsigned b = lds_off(&l8[(unsigned)lr * 3u]);
            ds_add_u64_nr(b,
                ((unsigned long long)(unsigned)q1 << 32) | (unsigned)(q0 + FXB));
            ds_add_u64_nr(b + 8,
                ((unsigned long long)(unsigned)q3 << 32) | (unsigned)(q2 + FXB));
            ds_add_u64_nr(b + 16,
                ((unsigned long long)((unsigned)q5 + NTAG) << 32) | (unsigned)(q4 + FXB));
        }
    }
    lgkm_drain();
    __syncthreads();

    float* dst = acc + (size_t)bin * (RB_PX * 6);
    for (int px = t; px < RB_PX; px += ACC_THREADS) {
        const unsigned long long a0 = l8[px * 3 + 0];
        const unsigned long long a1 = l8[px * 3 + 1];
        const unsigned long long a2 = l8[px * 3 + 2];
        const unsigned hi3 = (unsigned)(a2 >> 32);
        const unsigned n = hi3 >> 24;                     // record count
        const long long nb = (long long)n * FXB;
        float* d = dst + px * 6;
        d[0] = (float)((long long)(unsigned)(a0 & 0xFFFFFFFFull) - nb) * FXINV;
        d[1] = (float)((int)(a0 >> 32)) * FXINV;
        d[2] = (float)((long long)(unsigned)(a1 & 0xFFFFFFFFull) - nb) * FXINV;
        d[3] = (float)((int)(a1 >> 32)) * FXINV;
        d[4] = (float)((long long)(unsigned)(a2 & 0xFFFFFFFFull) - nb) * FXINV;
        d[5] = (float)(hi3 & 0xFFFFFFu) * FXINV;          // sum of vals (positive)
    }
}

// sum 4 shards per pixel, divide, write [BSZ][NPIX]
__global__ void k_reduce(const float* __restrict__ acc, float* __restrict__ out) {
    const int p = blockIdx.x * blockDim.x + threadIdx.x;
    if (p < NPIX) {
        const int rbin = p >> RB_SHIFT, lr = p & (RB_PX - 1);
        float n0 = 0.f, n1 = 0.f, n2 = 0.f, n3 = 0.f, n4 = 0.f, den = 0.f;
#pragma unroll
        for (int s = 0; s < NSHARD; ++s) {
            const float* b = acc + ((size_t)(rbin * NSHARD + s) * RB_PX + lr) * 6;
            n0 += b[0]; n1 += b[1]; n2 += b[2];
            n3 += b[3]; n4 += b[4]; den += b[5];
        }
        const float inv = 1.f / den;
        out[0 * (size_t)NPIX + p] = n0 * inv;
        out[1 * (size_t)NPIX + p] = n1 * inv;
        out[2 * (size_t)NPIX + p] = n2 * inv;
        out[3 * (size_t)NPIX + p] = n3 * inv;
        out[4 * (size_t)NPIX + p] = n4 * inv;
    }
}

// ---------------- fallback kernels (small workspace) ----------------

__global__ void bp_scatter_fb_kernel(const float* __restrict__ sino,
                                     const float* __restrict__ vals,
                                     const int*   __restrict__ rows,
                                     const int*   __restrict__ cols,
                                     float* __restrict__ acc) {
    const long long stride = (long long)gridDim.x * blockDim.x;
    for (long long i = (long long)blockIdx.x * blockDim.x + threadIdx.x;
         i < NNZ; i += stride) {
        const float v = vals[i];
        const int   r = rows[i];
        const int   c = cols[i];
        atomicAdd(acc + (size_t)BSZ * NPIX + r, v);
#pragma unroll
        for (int b = 0; b < BSZ; ++b)
            atomicAdd(acc + (size_t)b * NPIX + r, v * sino[(size_t)b * SINO + c]);
    }
}

__global__ void bp_divide_fb_kernel(const float* __restrict__ acc,
                                    float* __restrict__ out) {
    const int i = blockIdx.x * blockDim.x + threadIdx.x;
    if (i < BSZ * NPIX) {
        const int p = i % NPIX;
        out[i] = acc[i] / acc[(size_t)BSZ * NPIX + p];
    }
}

// ---------------- launch ----------------

extern "C" void kernel_launch(void* const* d_in, const int* in_sizes, int n_in,
                              void* d_out, int out_size, void* d_ws, size_t ws_size,
                              hipStream_t stream) {
    const float* sino = (const float*)d_in[0];
    const float* vals = (const float*)d_in[1];
    const int*   rows = (const int*)d_in[2];
    const int*   cols = (const int*)d_in[3];
    float* out = (float*)d_out;

    // workspace layout (bytes, all 16B-aligned):
    //   recA   : 512 bins * 51200 * 4     = 104,857,600
    //   recB   : 512 bins * 51200 * 2     =  52,428,800
    //   sino_b : SINO * 16                =   8,208,000
    //   acc    : NBIN * RB_PX * 6 * 4     =  12,582,912
    //   gcnt   : SCAT_BLOCKS * NBIN * 4   =     524,288
    //   ovf    : OVF_CAP * 8              =     524,288
    //   ovf_n  : 16
    //   total ~ 179.1 MB
    const size_t recA_b   = (size_t)NBIN * CELLS_PER_BIN * 4;
    const size_t recB_b   = (size_t)NBIN * CELLS_PER_BIN * 2;
    const size_t sino_b_b = (size_t)SINO * 16;
    const size_t acc_b    = (size_t)NBIN * RB_PX * 6 * 4;
    const size_t gcnt_b   = (size_t)SCAT_BLOCKS * NBIN * 4;
    const size_t ovf_b    = (size_t)OVF_CAP * 8;
    const size_t need = recA_b + recB_b + sino_b_b + acc_b + gcnt_b + ovf_b + 16;

    if (ws_size >= need) {
        char* w = (char*)d_ws;
        unsigned*       recA = (unsigned*)w;                w += recA_b;
        unsigned short* recB = (unsigned short*)w;          w += recB_b;
        u32x4*    sinob  = (u32x4*)w;                       w += sino_b_b;
        float*    acc    = (float*)w;                       w += acc_b;
        unsigned* gcnt   = (unsigned*)w;                    w += gcnt_b;
        unsigned long long* ovf = (unsigned long long*)w;   w += ovf_b;
        unsigned* ovf_n  = (unsigned*)w;

        (void)hipMemsetAsync(ovf_n, 0, 4, stream);
        k_scatter<<<SCAT_BLOCKS, SCT_THREADS, 0, stream>>>(
            sino, sinob, vals, rows, cols, recA, recB, gcnt, ovf, ovf_n);
        k_accum<<<NBIN, ACC_THREADS, 0, stream>>>(
            recA, recB, gcnt, sinob, ovf, ovf_n, acc);
        k_reduce<<<(NPIX + 255) / 256, 256, 0, stream>>>(acc, out);
    } else {
        float* acc = (float*)d_ws;
        (void)hipMemsetAsync(acc, 0, (size_t)(BSZ + 1) * NPIX * sizeof(float), stream);
        bp_scatter_fb_kernel<<<2048, 256, 0, stream>>>(sino, vals, rows, cols, acc);
        bp_divide_fb_kernel<<<(BSZ * NPIX + 255) / 256, 256, 0, stream>>>(acc, out);
    }
}